// Round 12
// baseline (769.065 us; speedup 1.0000x reference)
//
#include <hip/hip_runtime.h>

typedef unsigned short u16;
typedef unsigned int u32;
typedef __attribute__((ext_vector_type(8))) short short8;
typedef __attribute__((ext_vector_type(4))) short short4_t;
typedef __attribute__((ext_vector_type(4))) float float4_t;

#define B_ 4
#define LT_ 2048
#define LE_ 1024
#define D_ 1024
#define H_ 16
#define HD_ 64
#define NB_ 16
#define BS_ 128
#define M_ 4096
#define SCALE_ 0.125f

typedef __attribute__((address_space(1))) const void gas_t;
typedef __attribute__((address_space(3))) void las_t;

__device__ __forceinline__ float b2f(u16 u) {
  union { unsigned int i; float f; } v; v.i = ((unsigned int)u) << 16; return v.f;
}
__device__ __forceinline__ u16 f2b(float f) {
  union { float f; unsigned int i; } v; v.f = f;
  unsigned int x = v.i;
  return (u16)((x + 0x7fffu + ((x >> 16) & 1u)) >> 16);
}
__device__ __forceinline__ float gelu_f(float u) {
  // tanh-gelu via __expf: tanh(t) = 1 - 2/(exp(2t)+1)
  float t = 0.7978845608028654f * (u + 0.044715f * u * u * u);
  float th = 1.f - 2.f / (__expf(2.f * t) + 1.f);
  return 0.5f * u * (1.f + th);
}
__device__ __forceinline__ void store_val(u16* p, float x) { *p = f2b(x); }
__device__ __forceinline__ void store_val(float* p, float x) { *p = x; }

// ---------------- fp32 -> bf16 convert ----------------
__global__ __launch_bounds__(256)
void conv_k(const float* __restrict__ in, u16* __restrict__ out) {
  int i = (blockIdx.x * 256 + threadIdx.x) * 4;
  float4_t v = *(const float4_t*)(in + i);
  short4_t o;
  o[0] = (short)f2b(v[0]); o[1] = (short)f2b(v[1]);
  o[2] = (short)f2b(v[2]); o[3] = (short)f2b(v[3]);
  *(short4_t*)(out + i) = o;
}

// ---------------- transpose fp32 [R,Csub] (row stride) -> bf16 [Csub,R] ----------------
// (kept for the per-batch fallback path)
__global__ __launch_bounds__(256)
void transpose_k(const float* __restrict__ in, u16* __restrict__ out, int R, int rstride) {
  __shared__ u16 tile[32][33];
  int bx = blockIdx.x * 32, by = blockIdx.y * 32;
  int tx = threadIdx.x & 31, ty = threadIdx.x >> 5;
  #pragma unroll
  for (int y = ty; y < 32; y += 8)
    tile[y][tx] = f2b(in[(size_t)(by + y) * rstride + bx + tx]);
  __syncthreads();
  #pragma unroll
  for (int y = ty; y < 32; y += 8)
    out[(size_t)(bx + y) * R + by + tx] = tile[tx][y];
}

// ---------------- fused multi-transpose (one launch for all weight transposes) ----------
#define NJOBS 10
struct TJobs {
  const float* src[NJOBS];
  u16* dst[NJOBS];
  int outR[NJOBS];    // out row stride
  int inS[NJOBS];     // in row stride
  int ntx[NJOBS];     // tiles along out-row direction
  int ntiles[NJOBS];  // total tiles for this job
};

__global__ __launch_bounds__(256)
void prep_k(TJobs J) {
  int t = blockIdx.x, j = 0;
  while (t >= J.ntiles[j]) { t -= J.ntiles[j]; ++j; }   // uniform per block, <=10 iters
  const float* in = J.src[j];
  u16* out = J.dst[j];
  const int R = J.outR[j], rstride = J.inS[j];
  const int bx = (t % J.ntx[j]) * 32, by = (t / J.ntx[j]) * 32;
  __shared__ u16 tile[32][33];
  int tx = threadIdx.x & 31, ty = threadIdx.x >> 5;
  #pragma unroll
  for (int y = ty; y < 32; y += 8)
    tile[y][tx] = f2b(in[(size_t)(by + y) * rstride + bx + tx]);
  __syncthreads();
  #pragma unroll
  for (int y = ty; y < 32; y += 8)
    out[(size_t)(bx + y) * R + by + tx] = tile[tx][y];
}

// ---------------- layernorm (rows of 1024): fp32 in -> bf16 out ----------------
__global__ __launch_bounds__(256)
void ln_k(const float* __restrict__ x, const float* __restrict__ sw,
          const float* __restrict__ bw, u16* __restrict__ out) {
  int row = blockIdx.x, tid = threadIdx.x;
  const float* xr = x + (size_t)row * 1024 + tid * 4;
  float4_t raw = *(const float4_t*)xr;
  float v0 = raw[0], v1 = raw[1], v2 = raw[2], v3 = raw[3];
  float sum = v0 + v1 + v2 + v3;
  #pragma unroll
  for (int off = 32; off > 0; off >>= 1) sum += __shfl_down(sum, off, 64);
  __shared__ float sA[4], sB[4];
  int w = tid >> 6;
  if ((tid & 63) == 0) sA[w] = sum;
  __syncthreads();
  float mu = (sA[0] + sA[1] + sA[2] + sA[3]) * (1.f / 1024.f);
  float d0 = v0 - mu, d1 = v1 - mu, d2 = v2 - mu, d3 = v3 - mu;
  float s2 = d0 * d0 + d1 * d1 + d2 * d2 + d3 * d3;
  #pragma unroll
  for (int off = 32; off > 0; off >>= 1) s2 += __shfl_down(s2, off, 64);
  if ((tid & 63) == 0) sB[w] = s2;
  __syncthreads();
  float inv = rsqrtf((sB[0] + sB[1] + sB[2] + sB[3]) * (1.f / 1024.f) + 1e-6f);
  float4_t sv = *(const float4_t*)(sw + tid * 4);
  float4_t bv = *(const float4_t*)(bw + tid * 4);
  short4_t ov;
  ov[0] = (short)f2b(d0 * inv * sv[0] + bv[0]);
  ov[1] = (short)f2b(d1 * inv * sv[1] + bv[1]);
  ov[2] = (short)f2b(d2 * inv * sv[2] + bv[2]);
  ov[3] = (short)f2b(d3 * inv * sv[3] + bv[3]);
  *(short4_t*)(out + (size_t)row * 1024 + tid * 4) = ov;
}

// ---------------- MFMA GEMM (m97 structure, 2-barrier): fallback path only ------------
template<int EPI, typename TC, int SPLIT>
__global__ __launch_bounds__(256)
void gemm_k(const u16* __restrict__ A, const u16* __restrict__ Bt,
            const float* __restrict__ bias, const float* __restrict__ res,
            TC* __restrict__ C, int M, int N, int K, size_t cstride) {
  __shared__ __align__(16) u16 lA[128 * 32];
  __shared__ __align__(16) u16 lB[128 * 32];
  const int gx = gridDim.x;
  int lin = blockIdx.y * gx + blockIdx.x;
  const int nwg = gx * gridDim.y;
  if (!(nwg & 7)) {                    // all our grids are %8==0
    const int chunk = nwg >> 3;
    lin = (lin & 7) * chunk + (lin >> 3);
  }
  const int bn = (lin % gx) * 128;
  const int bm = (lin / gx) * 128;
  const int tid = threadIdx.x;
  const int lane = tid & 63;
  const int wave = tid >> 6;
  const int wy = wave >> 1, wx = wave & 1;
  const int quad = lane >> 4, l16 = lane & 15;

  float4_t acc[4][4];
  float4_t zz = {0.f, 0.f, 0.f, 0.f};
  #pragma unroll
  for (int i = 0; i < 4; ++i)
    #pragma unroll
    for (int j = 0; j < 4; ++j) acc[i][j] = zz;

  const int r0 = tid >> 2, kc0 = (tid & 3) * 8;       // u=0 chunk
  const u16* gA0 = A + (size_t)(bm + r0) * K + kc0;
  const u16* gA1 = A + (size_t)(bm + 64 + r0) * K + kc0;
  const u16* gB0 = Bt + (size_t)(bn + r0) * K + kc0;
  const u16* gB1 = Bt + (size_t)(bn + 64 + r0) * K + kc0;
  u16* lA0 = &lA[tid * 8];
  u16* lA1 = &lA[(tid + 256) * 8];
  u16* lB0 = &lB[tid * 8];
  u16* lB1 = &lB[(tid + 256) * 8];

  for (int k0 = 0; k0 < K; k0 += 32) {
    __syncthreads();
    __builtin_amdgcn_global_load_lds((gas_t*)(gA0 + k0), (las_t*)lA0, 16, 0, 0);
    __builtin_amdgcn_global_load_lds((gas_t*)(gA1 + k0), (las_t*)lA1, 16, 0, 0);
    __builtin_amdgcn_global_load_lds((gas_t*)(gB0 + k0), (las_t*)lB0, 16, 0, 0);
    __builtin_amdgcn_global_load_lds((gas_t*)(gB1 + k0), (las_t*)lB1, 16, 0, 0);
    __syncthreads();
    short8 af[4], bfr[4];
    #pragma unroll
    for (int i = 0; i < 4; ++i)
      af[i] = *(const short8*)&lA[(wy * 64 + i * 16 + l16) * 32 + quad * 8];
    #pragma unroll
    for (int j = 0; j < 4; ++j)
      bfr[j] = *(const short8*)&lB[(wx * 64 + j * 16 + l16) * 32 + quad * 8];
    #pragma unroll
    for (int i = 0; i < 4; ++i)
      #pragma unroll
      for (int j = 0; j < 4; ++j)
        acc[i][j] = __builtin_amdgcn_mfma_f32_16x16x32_bf16(af[i], bfr[j], acc[i][j], 0, 0, 0);
  }

  #pragma unroll
  for (int i = 0; i < 4; ++i) {
    int row = bm + wy * 64 + i * 16 + quad * 4;
    #pragma unroll
    for (int j = 0; j < 4; ++j) {
      int col = bn + wx * 64 + j * 16 + l16;
      TC* Cb = SPLIT ? (C + (size_t)(col >> 10) * cstride) : C;
      int ccol = SPLIT ? (col & 1023) : col;
      int cn = SPLIT ? 1024 : N;
      #pragma unroll
      for (int v = 0; v < 4; ++v) {
        float x = acc[i][j][v];
        size_t idx = (size_t)(row + v) * cn + ccol;
        if (EPI == 1) {
          x += res[idx];
        } else if (EPI == 2) {
          x = gelu_f(x + bias[col]);
        } else if (EPI == 3) {
          x += bias[col] + res[idx];
        }
        store_val(&Cb[idx], x);
      }
    }
  }
}

// ---------------- 128x128 deep-pipelined GEMM (counted-vmcnt, 2 blocks/CU) ----------
// Round-11 profile showed SQ_LDS_BANK_CONFLICT 8.4M (inherited m97 pattern:
// lanes at rows r,r+2 share one 4-bank group -> 8-way on ds_read_b128), and
// MLP1 slower than swizzled gemm256 (126 vs 112us). NEW: slot-XOR swizzle.
// Stage pre-swizzles the GLOBAL source column (LDS dest stays linear, per
// m104/m173): kc0 = ((tid&3)^((tid>>2)&3))*8; +256 chunk's row differs by 64
// (=0 mod 4) so same XOR. Read: slo = (quad^(l16&3))*8 (row=...+l16, row&3 =
// l16&3). Involution verified; 4 consecutive rows -> 4 distinct bank groups,
// 2-way residual = free (m136). gemm256 (same swizzle idea) measured 0 conflicts.
template<int EPI, typename TC, int SPLIT>
__global__ __launch_bounds__(256, 2)
void gemm128d_k(const u16* __restrict__ A, const u16* __restrict__ Bt,
                const float* __restrict__ bias, const float* __restrict__ res,
                TC* __restrict__ C, int M, int N, int K, size_t cstride) {
  __shared__ __align__(16) u16 lA[4][128 * 32];
  __shared__ __align__(16) u16 lB[4][128 * 32];
  const int gx = gridDim.x;
  int lin = blockIdx.y * gx + blockIdx.x;
  const int nwg = gx * gridDim.y;
  if (!(nwg & 7)) {
    const int chunk = nwg >> 3;
    lin = (lin & 7) * chunk + (lin >> 3);
  }
  const int bn = (lin % gx) * 128;
  const int bm = (lin / gx) * 128;
  const int tid = threadIdx.x;
  const int lane = tid & 63;
  const int wave = tid >> 6;
  const int wy = wave >> 1, wx = wave & 1;
  const int quad = lane >> 4, l16 = lane & 15;
  const int slo = (quad ^ (l16 & 3)) * 8;     // swizzled 8-elem slot (read side)

  float4_t acc[4][4];
  float4_t zz = {0.f, 0.f, 0.f, 0.f};
  #pragma unroll
  for (int i = 0; i < 4; ++i)
    #pragma unroll
    for (int j = 0; j < 4; ++j) acc[i][j] = zz;

  const int r0 = tid >> 2;
  const int kc0 = ((tid & 3) ^ (r0 & 3)) * 8;  // pre-swizzled global k-column
  const u16* gA0 = A + (size_t)(bm + r0) * K + kc0;
  const u16* gA1 = A + (size_t)(bm + 64 + r0) * K + kc0;
  const u16* gB0 = Bt + (size_t)(bn + r0) * K + kc0;
  const u16* gB1 = Bt + (size_t)(bn + 64 + r0) * K + kc0;
  const int NT = K >> 5;

  #define STAGE128(TT, BUF)                                                      \
    {                                                                            \
      int kk_ = (TT) * 32;                                                       \
      __builtin_amdgcn_global_load_lds((gas_t*)(gA0 + kk_),                      \
          (las_t*)&lA[BUF][tid * 8], 16, 0, 0);                                  \
      __builtin_amdgcn_global_load_lds((gas_t*)(gA1 + kk_),                      \
          (las_t*)&lA[BUF][(tid + 256) * 8], 16, 0, 0);                          \
      __builtin_amdgcn_global_load_lds((gas_t*)(gB0 + kk_),                      \
          (las_t*)&lB[BUF][tid * 8], 16, 0, 0);                                  \
      __builtin_amdgcn_global_load_lds((gas_t*)(gB1 + kk_),                      \
          (las_t*)&lB[BUF][(tid + 256) * 8], 16, 0, 0);                          \
    }

  STAGE128(0, 0)
  STAGE128(1, 1)
  STAGE128(2, 2)

  for (int t = 0; t < NT; ++t) {
    asm volatile("s_waitcnt vmcnt(8)" ::: "memory");   // tile t resident; t+1,t+2 in flight
    __builtin_amdgcn_s_barrier();
    __builtin_amdgcn_sched_barrier(0);
    int ts = t + 3; if (ts > NT - 1) ts = NT - 1;      // tail: dummy re-stage, dead buffer
    STAGE128(ts, (t + 3) & 3)
    const u16* bufA = &lA[t & 3][0];
    const u16* bufB = &lB[t & 3][0];
    short8 af[4], bfr[4];
    #pragma unroll
    for (int i = 0; i < 4; ++i)
      af[i] = *(const short8*)&bufA[(wy * 64 + i * 16 + l16) * 32 + slo];
    #pragma unroll
    for (int j = 0; j < 4; ++j)
      bfr[j] = *(const short8*)&bufB[(wx * 64 + j * 16 + l16) * 32 + slo];
    __builtin_amdgcn_s_setprio(1);
    #pragma unroll
    for (int i = 0; i < 4; ++i)
      #pragma unroll
      for (int j = 0; j < 4; ++j)
        acc[i][j] = __builtin_amdgcn_mfma_f32_16x16x32_bf16(af[i], bfr[j], acc[i][j], 0, 0, 0);
    __builtin_amdgcn_s_setprio(0);
  }
  #undef STAGE128

  #pragma unroll
  for (int i = 0; i < 4; ++i) {
    int row = bm + wy * 64 + i * 16 + quad * 4;
    #pragma unroll
    for (int j = 0; j < 4; ++j) {
      int col = bn + wx * 64 + j * 16 + l16;
      TC* Cb = SPLIT ? (C + (size_t)(col >> 10) * cstride) : C;
      int ccol = SPLIT ? (col & 1023) : col;
      int cn = SPLIT ? 1024 : N;
      #pragma unroll
      for (int v = 0; v < 4; ++v) {
        float x = acc[i][j][v];
        size_t idx = (size_t)(row + v) * cn + ccol;
        if (EPI == 1) {
          x += res[idx];
        } else if (EPI == 2) {
          x = gelu_f(x + bias[col]);
        } else if (EPI == 3) {
          x += bias[col] + res[idx];
        }
        store_val(&Cb[idx], x);
      }
    }
  }
}

// ---------------- 256x256 deep-pipelined MFMA GEMM (counted-vmcnt) -----------------
// Retained for reference/fallback (1 block/CU quantization at small grids).
template<int EPI, typename TC, int SPLIT>
__global__ __launch_bounds__(512, 2)
void gemm256_k(const u16* __restrict__ A, const u16* __restrict__ Bt,
               const float* __restrict__ bias, const float* __restrict__ res,
               TC* __restrict__ C, int M, int N, int K, size_t cstride) {
  __shared__ __align__(16) u16 lA[4][256 * 32];
  __shared__ __align__(16) u16 lB[4][256 * 32];
  const int gx = gridDim.x;
  int lin = blockIdx.y * gx + blockIdx.x;
  const int nwg = gx * gridDim.y;
  if (!(nwg & 7)) {
    const int chunk = nwg >> 3;
    lin = (lin & 7) * chunk + (lin >> 3);
  }
  const int bn = (lin % gx) * 256;
  const int bm = (lin / gx) * 256;
  const int tid = threadIdx.x;
  const int lane = tid & 63;
  const int wave = tid >> 6;
  const int wy = wave >> 2, wx = wave & 3;        // 2 x 4 waves
  const int quad = lane >> 4, l16 = lane & 15;
  const int slo = ((quad ^ ((l16 >> 1) & 3)) << 4);  // swizzled 16B slot (bytes)

  int lrow[2], kcs[2];
  #pragma unroll
  for (int u = 0; u < 2; ++u) {
    int p = (tid + u * 512) * 16;
    int lg = p ^ (((p >> 7) & 3) << 4);
    lrow[u] = lg >> 6;
    kcs[u] = (lg & 63) >> 1;
  }
  const u16* gA[2]; const u16* gB[2];
  #pragma unroll
  for (int u = 0; u < 2; ++u) {
    gA[u] = A + (size_t)(bm + lrow[u]) * K + kcs[u];
    gB[u] = Bt + (size_t)(bn + lrow[u]) * K + kcs[u];
  }
  const int NT = K >> 5;

  float4_t acc[8][4];
  float4_t zz = {0.f, 0.f, 0.f, 0.f};
  #pragma unroll
  for (int i = 0; i < 8; ++i)
    #pragma unroll
    for (int j = 0; j < 4; ++j) acc[i][j] = zz;

  #define STAGE256(TT, BUF)                                                      \
    {                                                                            \
      int kk_ = (TT) * 32;                                                       \
      __builtin_amdgcn_global_load_lds((gas_t*)(gA[0] + kk_),                    \
          (las_t*)((char*)&lA[BUF][0] + tid * 16), 16, 0, 0);                    \
      __builtin_amdgcn_global_load_lds((gas_t*)(gA[1] + kk_),                    \
          (las_t*)((char*)&lA[BUF][0] + (tid + 512) * 16), 16, 0, 0);            \
      __builtin_amdgcn_global_load_lds((gas_t*)(gB[0] + kk_),                    \
          (las_t*)((char*)&lB[BUF][0] + tid * 16), 16, 0, 0);                    \
      __builtin_amdgcn_global_load_lds((gas_t*)(gB[1] + kk_),                    \
          (las_t*)((char*)&lB[BUF][0] + (tid + 512) * 16), 16, 0, 0);            \
    }

  STAGE256(0, 0)
  STAGE256(1, 1)
  STAGE256(2, 2)

  for (int t = 0; t < NT; ++t) {
    asm volatile("s_waitcnt vmcnt(8)" ::: "memory");   // tile t resident; t+1,t+2 in flight
    __builtin_amdgcn_s_barrier();
    __builtin_amdgcn_sched_barrier(0);
    int ts = t + 3; if (ts > NT - 1) ts = NT - 1;      // tail: dummy re-stage, dead buffer
    STAGE256(ts, (t + 3) & 3)
    const char* bufA = (const char*)&lA[t & 3][0];
    const char* bufB = (const char*)&lB[t & 3][0];
    short8 af[8], bf[4];
    #pragma unroll
    for (int i = 0; i < 8; ++i)
      af[i] = *(const short8*)(bufA + (wy * 128 + i * 16 + l16) * 64 + slo);
    #pragma unroll
    for (int j = 0; j < 4; ++j)
      bf[j] = *(const short8*)(bufB + (wx * 64 + j * 16 + l16) * 64 + slo);
    __builtin_amdgcn_s_setprio(1);
    #pragma unroll
    for (int i = 0; i < 8; ++i)
      #pragma unroll
      for (int j = 0; j < 4; ++j)
        acc[i][j] = __builtin_amdgcn_mfma_f32_16x16x32_bf16(af[i], bf[j], acc[i][j], 0, 0, 0);
    __builtin_amdgcn_s_setprio(0);
  }
  #undef STAGE256

  #pragma unroll
  for (int i = 0; i < 8; ++i) {
    int row = bm + wy * 128 + i * 16 + quad * 4;
    #pragma unroll
    for (int j = 0; j < 4; ++j) {
      int col = bn + wx * 64 + j * 16 + l16;
      TC* Cb = SPLIT ? (C + (size_t)(col >> 10) * cstride) : C;
      int ccol = SPLIT ? (col & 1023) : col;
      int cn = SPLIT ? 1024 : N;
      #pragma unroll
      for (int v = 0; v < 4; ++v) {
        float x = acc[i][j][v];
        size_t idx = (size_t)(row + v) * cn + ccol;
        if (EPI == 1) {
          x += res[idx];
        } else if (EPI == 2) {
          x = gelu_f(x + bias[col]);
        } else if (EPI == 3) {
          x += bias[col] + res[idx];
        }
        store_val(&Cb[idx], x);
      }
    }
  }
}

// ---------------- krep: sum k over block rows (b decoded from idx) ----------------
__global__ __launch_bounds__(256)
void krep_k(const u16* __restrict__ K1, float* __restrict__ krep) {
  int idx = blockIdx.x * 256 + threadIdx.x;   // (#batches)*NB*1024
  int col = idx & 1023;
  int bn = idx >> 10;
  const u16* p = K1 + (size_t)bn * 128 * 1024 + col;
  float s = 0.f;
  for (int i = 0; i < 128; ++i) s += b2f(p[(size_t)i * 1024]);
  krep[idx] = s;
}

// ---------------- sinkhorn: grid = (#batches)*H, one (b,h) each ----------------
__global__ __launch_bounds__(256)
void sinkhorn_k(const float* __restrict__ krep, const float* __restrict__ wsort,
                float* __restrict__ P) {
  int bh = blockIdx.x;
  int b = bh >> 4, h = bh & 15;
  int t = threadIdx.x;
  int i = t >> 4, j = t & 15;
  __shared__ float la[16][17];
  __shared__ float red[16];
  float acc = 0.f;
  const float* kr = krep + ((size_t)b * 16 + i) * 1024 + h * 64;
  const float* ws = wsort + (size_t)h * 64 * 16 + j;
  for (int k = 0; k < 64; ++k) acc += kr[k] * ws[k * 16];
  la[i][j] = (j <= i) ? acc : -1e9f;
  __syncthreads();
  for (int it = 0; it < 5; ++it) {
    if (t < 16) {
      float m = -1e30f;
      for (int jj = 0; jj < 16; ++jj) m = fmaxf(m, la[t][jj]);
      float s = 0.f;
      for (int jj = 0; jj < 16; ++jj) s += __expf(la[t][jj] - m);
      red[t] = m + __logf(s);
    }
    __syncthreads();
    la[i][j] = (j <= i) ? la[i][j] - red[i] : -1e9f;
    __syncthreads();
    if (t < 16) {
      float m = -1e30f;
      for (int ii = 0; ii < 16; ++ii) m = fmaxf(m, la[ii][t]);
      float s = 0.f;
      for (int ii = 0; ii < 16; ++ii) s += __expf(la[ii][t] - m);
      red[t] = m + __logf(s);
    }
    __syncthreads();
    la[i][j] = (j <= i) ? la[i][j] - red[j] : -1e9f;
    __syncthreads();
  }
  P[((size_t)bh * 16 + i) * 16 + j] = __expf(la[i][j]);
}

// ---------------- sorted block mix (b decoded from idx), short8 loads ----------------
__global__ __launch_bounds__(256)
void sortmix_k(const float* __restrict__ P, const u16* __restrict__ K1,
               const u16* __restrict__ V1, u16* __restrict__ KS,
               u16* __restrict__ VS) {
  int t = blockIdx.x * 256 + threadIdx.x;     // (#batches)*2048*128 (8 cols each)
  int col = (t & 127) * 8;
  int rest = t >> 7;                          // b*2048 + i*128 + s
  int b = rest >> 11, is = rest & 2047, i = is >> 7, s = is & 127;
  int h = col >> 6;                           // 8-col chunk never straddles a head
  const float* Pr = P + (((size_t)(b * 16 + h)) * 16 + i) * 16;
  size_t base = ((size_t)(b * 2048 + s)) * 1024 + col;
  float ka[8] = {0, 0, 0, 0, 0, 0, 0, 0}, va[8] = {0, 0, 0, 0, 0, 0, 0, 0};
  for (int j = 0; j <= i; ++j) {   // P[i][j]==0 for j>i (causal mask)
    float p = Pr[j];
    short8 kk = *(const short8*)&K1[base + (size_t)j * 131072];
    short8 vv = *(const short8*)&V1[base + (size_t)j * 131072];
    #pragma unroll
    for (int e = 0; e < 8; ++e) {
      ka[e] += p * b2f((u16)kk[e]);
      va[e] += p * b2f((u16)vv[e]);
    }
  }
  size_t ob = ((size_t)(b * 2048 + i * 128 + s)) * 1024 + col;
  short8 ok, ov;
  #pragma unroll
  for (int e = 0; e < 8; ++e) { ok[e] = (short)f2b(ka[e]); ov[e] = (short)f2b(va[e]); }
  *(short8*)&KS[ob] = ok;
  *(short8*)&VS[ob] = ov;
}

// ---------------- MFMA flash attention (conflict-free LDS redesign) ----------------
// Verified correct on HW rounds 8-11. kls XOR-swizzled, V transposed via 2-pass
// LDS (b128 writes), P in registers via shfl-assembled PV A-fragments.
template<int CROSS>
__global__ __launch_bounds__(256)
void attn_mfma_k(const u16* __restrict__ Q, const u16* __restrict__ Ka,
                 const u16* __restrict__ Va, const u16* __restrict__ Kb2,
                 const u16* __restrict__ Vb2, u16* __restrict__ O) {
  __shared__ __align__(16) u16 kls[128 * 64];
  __shared__ __align__(16) u16 vlin[128 * 64];
  __shared__ __align__(16) u16 vtls[64 * 128];
  int blk = blockIdx.x;
  {
    int nwg = gridDim.x;
    if (!(nwg & 7)) { int ch = nwg >> 3; blk = (blk & 7) * ch + (blk >> 3); }
  }
  const int n = blk & 15, h = (blk >> 4) & 15, b = blk >> 8;
  const int tid = threadIdx.x, lane = tid & 63, wv = tid >> 6;
  const int quad = lane >> 4, l16 = lane & 15;
  const int m0 = wv * 32;
  const size_t qrowbase = (size_t)b * 2048 + n * 128;

  short8 qa[2][2];
  #pragma unroll
  for (int qi = 0; qi < 2; ++qi)
    #pragma unroll
    for (int ks = 0; ks < 2; ++ks)
      qa[qi][ks] = *(const short8*)&Q[(qrowbase + m0 + qi * 16 + l16) * 1024 +
                                      h * 64 + ks * 32 + quad * 8];

  float4_t acc_o[2][4];
  float mrow[2], lrow[2];
  #pragma unroll
  for (int mi = 0; mi < 2; ++mi) {
    #pragma unroll
    for (int dn = 0; dn < 4; ++dn) acc_o[mi][dn] = {0.f, 0.f, 0.f, 0.f};
    mrow[mi] = -1e30f; lrow[mi] = 0.f;
  }

  const int NT = CROSS ? 8 : 2;
  for (int t = 0; t < NT; ++t) {
    const u16 *Kg, *Vg;
    bool causal = false;
    if (CROSS) {
      size_t kb = ((size_t)b * 1024 + t * 128) * 1024 + h * 64;
      Kg = Ka + kb; Vg = Va + kb;
    } else if (t == 0) {
      size_t kb = qrowbase * 1024 + h * 64;
      Kg = Ka + kb; Vg = Va + kb; causal = true;
    } else {
      size_t kb = qrowbase * 1024 + h * 64;
      Kg = Kb2 + kb; Vg = Vb2 + kb;
    }
    // ---- stage K (swizzled) + V (linear) ----
    #pragma unroll
    for (int i = 0; i < 4; ++i) {
      int c = tid + i * 256;
      int row = c >> 3, slot = c & 7, dd = slot * 8;
      short8 kv8 = *(const short8*)&Kg[(size_t)row * 1024 + dd];
      *(short8*)&kls[row * 64 + ((slot ^ (row & 7)) * 8)] = kv8;
      short8 vv8 = *(const short8*)&Vg[(size_t)row * 1024 + dd];
      *(short8*)&vlin[row * 64 + dd] = vv8;
    }
    __syncthreads();                       // bar1: staging visible

    // ---- transpose vlin -> vtls (conflict-free) ----
    #pragma unroll
    for (int ii = 0; ii < 4; ++ii) {
      int d = tid & 63;
      int kvg = (tid >> 6) * 4 + ii;       // 0..15
      union { short8 s8; u16 us[8]; } tt;
      #pragma unroll
      for (int j = 0; j < 8; ++j)
        tt.us[j] = vlin[(kvg * 8 + j) * 64 + d];
      int slotp = (kvg & 8) | ((kvg ^ (d & 7)) & 7);
      *(short8*)&vtls[d * 128 + slotp * 8] = tt.s8;
    }

    // ---- QK^T, swapped operands: s[qi][nj] holds S^T (kv on quad*4+v, q on l16)
    float4_t s[2][8];
    #pragma unroll
    for (int qi = 0; qi < 2; ++qi)
      #pragma unroll
      for (int nj = 0; nj < 8; ++nj) s[qi][nj] = {0.f, 0.f, 0.f, 0.f};
    #pragma unroll
    for (int nj = 0; nj < 8; ++nj) {
      int r = nj * 16 + l16;
      short8 k0 = *(const short8*)&kls[r * 64 + ((quad ^ (l16 & 7)) * 8)];
      short8 k1 = *(const short8*)&kls[r * 64 + (((4 + quad) ^ (l16 & 7)) * 8)];
      #pragma unroll
      for (int qi = 0; qi < 2; ++qi) {
        s[qi][nj] = __builtin_amdgcn_mfma_f32_16x16x32_bf16(k0, qa[qi][0], s[qi][nj], 0, 0, 0);
        s[qi][nj] = __builtin_amdgcn_mfma_f32_16x16x32_bf16(k1, qa[qi][1], s[qi][nj], 0, 0, 0);
      }
    }

    // ---- lane-local online softmax; P kept in registers as bf16 pairs
    float crv[2];
    u32 p01[2][8], p23[2][8];
    #pragma unroll
    for (int qi = 0; qi < 2; ++qi) {
      const int qrow = m0 + qi * 16 + l16;     // block-local q row
      float mx = -1e30f;
      #pragma unroll
      for (int nj = 0; nj < 8; ++nj)
        #pragma unroll
        for (int v = 0; v < 4; ++v) {
          float x = s[qi][nj][v] * SCALE_;
          if (causal && (nj * 16 + quad * 4 + v > qrow)) x = -1e30f;
          s[qi][nj][v] = x;
          mx = fmaxf(mx, x);
        }
      mx = fmaxf(mx, __shfl_xor(mx, 16, 64));
      mx = fmaxf(mx, __shfl_xor(mx, 32, 64));
      float mn = fmaxf(mrow[qi], mx);
      crv[qi] = __expf(mrow[qi] - mn);
      mrow[qi] = mn;
      float rs = 0.f;
      #pragma unroll
      for (int nj = 0; nj < 8; ++nj)
        #pragma unroll
        for (int v = 0; v < 4; ++v) {
          float p = __expf(s[qi][nj][v] - mn);
          s[qi][nj][v] = p;
          rs += p;
        }
      rs += __shfl_xor(rs, 16, 64);
      rs += __shfl_xor(rs, 32, 64);
      lrow[qi] = lrow[qi] * crv[qi] + rs;
      #pragma unroll
      for (int nj = 0; nj < 8; ++nj) {
        p01[qi][nj] = (u32)f2b(s[qi][nj][0]) | ((u32)f2b(s[qi][nj][1]) << 16);
        p23[qi][nj] = (u32)f2b(s[qi][nj][2]) | ((u32)f2b(s[qi][nj][3]) << 16);
      }
    }
    // rescale accumulator: acc_o rows are q = m0 + mi*16 + quad*4 + v,
    // whose cr lives in lane l16 = quad*4+v (any quad; pick same quad).
    #pragma unroll
    for (int mi = 0; mi < 2; ++mi)
      #pragma unroll
      for (int v = 0; v < 4; ++v) {
        float c = __shfl(crv[mi], quad * 20 + v, 64);
        #pragma unroll
        for (int dn = 0; dn < 4; ++dn) acc_o[mi][dn][v] *= c;
      }

    __syncthreads();                       // bar2: vtls transpose visible

    // ---- PV: A-frag assembled in-register via shfl; B-frag from swizzled vtls
    const int src0 = (quad & 1) * 32 + l16;   // qs0*16 + l16
    const int src1 = src0 + 16;
    const bool hi = (quad >> 1) != 0;
    #pragma unroll
    for (int ks = 0; ks < 4; ++ks) {
      union { short8 s8; u32 u[4]; } au[2];
      #pragma unroll
      for (int qi = 0; qi < 2; ++qi) {
        u32 w0a = __shfl(p01[qi][2 * ks],     src0, 64);
        u32 w0b = __shfl(p01[qi][2 * ks + 1], src0, 64);
        u32 w1a = __shfl(p23[qi][2 * ks],     src0, 64);
        u32 w1b = __shfl(p23[qi][2 * ks + 1], src0, 64);
        u32 w2a = __shfl(p01[qi][2 * ks],     src1, 64);
        u32 w2b = __shfl(p01[qi][2 * ks + 1], src1, 64);
        u32 w3a = __shfl(p23[qi][2 * ks],     src1, 64);
        u32 w3b = __shfl(p23[qi][2 * ks + 1], src1, 64);
        au[qi].u[0] = hi ? w0b : w0a;
        au[qi].u[1] = hi ? w1b : w1a;
        au[qi].u[2] = hi ? w2b : w2a;
        au[qi].u[3] = hi ? w3b : w3a;
      }
      #pragma unroll
      for (int dn = 0; dn < 4; ++dn) {
        int dR = dn * 16 + l16;
        int sbase = ks * 4 + quad;
        int sp = (sbase & 8) | ((sbase ^ (l16 & 7)) & 7);
        short8 bv = *(const short8*)&vtls[dR * 128 + sp * 8];
        acc_o[0][dn] = __builtin_amdgcn_mfma_f32_16x16x32_bf16(au[0].s8, bv, acc_o[0][dn], 0, 0, 0);
        acc_o[1][dn] = __builtin_amdgcn_mfma_f32_16x16x32_bf16(au[1].s8, bv, acc_o[1][dn], 0, 0, 0);
      }
    }
  }
  #pragma unroll
  for (int mi = 0; mi < 2; ++mi) {
    float invl = 1.f / lrow[mi];
    #pragma unroll
    for (int v = 0; v < 4; ++v) {
      float inv = __shfl(invl, quad * 20 + v, 64);
      int rowl = m0 + mi * 16 + quad * 4 + v;
      #pragma unroll
      for (int dn = 0; dn < 4; ++dn)
        O[(qrowbase + rowl) * 1024 + h * 64 + dn * 16 + l16] =
            f2b(acc_o[mi][dn][v] * inv);
    }
  }
}

// ---------------- host ----------------
extern "C" void kernel_launch(void* const* d_in, const int* in_sizes, int n_in,
                              void* d_out, int out_size, void* d_ws, size_t ws_size,
                              hipStream_t stream) {
  const float* targets = (const float*)d_in[0];
  const float* encoded = (const float*)d_in[1];
  const float* ln1s = (const float*)d_in[2];
  const float* ln1b = (const float*)d_in[3];
  const float* ln2s = (const float*)d_in[4];
  const float* ln2b = (const float*)d_in[5];
  const float* ln3s = (const float*)d_in[6];
  const float* ln3b = (const float*)d_in[7];
  const float* wq1 = (const float*)d_in[8];
  const float* wk1 = (const float*)d_in[9];
  const float* wv1 = (const float*)d_in[10];
  const float* wo1 = (const float*)d_in[11];
  const float* wsort = (const float*)d_in[12];
  const float* wq2 = (const float*)d_in[13];
  const float* wk2 = (const float*)d_in[14];
  const float* wv2 = (const float*)d_in[15];
  const float* wo2 = (const float*)d_in[16];
  const float* w1 = (const float*)d_in[17];
  const float* b1 = (const float*)d_in[18];
  const float* w2 = (const float*)d_in[19];
  const float* b2 = (const float*)d_in[20];
  float* out = (float*)d_out;
  (void)in_sizes; (void)n_in; (void)out_size;

  char* ws = (char*)d_ws;
  size_t off = 0;
  auto alloc = [&](size_t n) -> char* {
    char* p = ws + off;
    off += (n + 255) & ~(size_t)255;
    return p;
  };

  const size_t NTD = (size_t)B_ * LT_ * D_;         // 8.4M elems
  const size_t NEED_BIG = (size_t)(8 * 2 + 8 + 8) * 1024 * 1024   // weights bf16
                        + (size_t)LE_ * B_ * D_ * 2                // Eb
                        + NTD * 2 * 7                              // XLN + 6 act
                        + (1u << 20);                              // small + slack

  if (ws_size >= NEED_BIG) {
    // ---------- whole-batch path ----------
    u16* wq1t = (u16*)alloc((size_t)1024 * 1024 * 2);
    u16* wk1t = (u16*)alloc((size_t)1024 * 1024 * 2);
    u16* wv1t = (u16*)alloc((size_t)1024 * 1024 * 2);
    u16* wo1t = (u16*)alloc((size_t)1024 * 1024 * 2);
    u16* wq2t = (u16*)alloc((size_t)1024 * 1024 * 2);
    u16* wk2t = (u16*)alloc((size_t)1024 * 1024 * 2);
    u16* wv2t = (u16*)alloc((size_t)1024 * 1024 * 2);
    u16* wo2t = (u16*)alloc((size_t)1024 * 1024 * 2);
    u16* w1t = (u16*)alloc((size_t)4096 * 1024 * 2);
    u16* w2t = (u16*)alloc((size_t)1024 * 4096 * 2);
    u16* Eb  = (u16*)alloc((size_t)B_ * LE_ * D_ * 2);
    u16* XLN = (u16*)alloc(NTD * 2);
    u16* Qb  = (u16*)alloc(NTD * 2);    // Qb..KSb (67.1MB contiguous) = MLP hidden
    u16* Kb  = (u16*)alloc(NTD * 2);
    u16* Vb  = (u16*)alloc(NTD * 2);
    u16* KSb = (u16*)alloc(NTD * 2);
    u16* VSb = (u16*)alloc(NTD * 2);
    u16* Ob  = (u16*)alloc(NTD * 2);
    float* KREP = (float*)alloc((size_t)B_ * NB_ * 1024 * 4);
    float* Pm = (float*)alloc((size_t)B_ * H_ * NB_ * NB_ * 4);
    u16* HML = Qb;

    // one fused launch for all 10 weight transposes
    TJobs J;
    const float* srcs[NJOBS] = {wq1, wk1, wv1, wo1, wq2, wk2, wv2, wo2, w1, w2};
    u16* dsts[NJOBS] = {wq1t, wk1t, wv1t, wo1t, wq2t, wk2t, wv2t, wo2t, w1t, w2t};
    int total = 0;
    for (int j = 0; j < NJOBS; ++j) {
      J.src[j] = srcs[j]; J.dst[j] = dsts[j];
      if (j < 8)      { J.outR[j] = 1024; J.inS[j] = 1024; J.ntx[j] = 32;  J.ntiles[j] = 1024; }
      else if (j == 8){ J.outR[j] = 1024; J.inS[j] = 4096; J.ntx[j] = 128; J.ntiles[j] = 4096; }
      else            { J.outR[j] = 4096; J.inS[j] = 1024; J.ntx[j] = 32;  J.ntiles[j] = 4096; }
      total += J.ntiles[j];
    }
    prep_k<<<total, 256, 0, stream>>>(J);
    conv_k<<<4096, 256, 0, stream>>>(encoded, Eb);

    ln_k<<<8192, 256, 0, stream>>>(targets, ln1s, ln1b, XLN);
    // fused QKV projection on 128^2 deep-pipelined kernel: 1536 blocks at
    // 2/CU = 3 exactly-full rounds
    gemm128d_k<0, u16, 1><<<dim3(24, 64), 256, 0, stream>>>(XLN, wq1t, nullptr, nullptr,
                                                            Qb, 8192, 3072, 1024, NTD);
    krep_k<<<256, 256, 0, stream>>>(Kb, KREP);
    sinkhorn_k<<<64, 256, 0, stream>>>(KREP, wsort, Pm);
    sortmix_k<<<4096, 256, 0, stream>>>(Pm, Kb, Vb, KSb, VSb);
    attn_mfma_k<0><<<1024, 256, 0, stream>>>(Qb, Kb, Vb, KSb, VSb, Ob);
    gemm128d_k<1, float, 0><<<dim3(8, 64), 256, 0, stream>>>(Ob, wo1t, nullptr, targets, out, 8192, 1024, 1024, 0);
    ln_k<<<8192, 256, 0, stream>>>(out, ln2s, ln2b, XLN);
    gemm128d_k<0, u16, 0><<<dim3(8, 64), 256, 0, stream>>>(XLN, wq2t, nullptr, nullptr, Qb, 8192, 1024, 1024, 0);
    // fused K2/V2 projection of encoded: Bt = [wk2t;wv2t] (N=2048), split -> Kb/Vb
    gemm128d_k<0, u16, 1><<<dim3(16, 32), 256, 0, stream>>>(Eb, wk2t, nullptr, nullptr, Kb, 4096, 2048, 1024, NTD);
    attn_mfma_k<1><<<1024, 256, 0, stream>>>(Qb, Kb, Vb, nullptr, nullptr, Ob);
    gemm128d_k<1, float, 0><<<dim3(8, 64), 256, 0, stream>>>(Ob, wo2t, nullptr, out, out, 8192, 1024, 1024, 0);
    ln_k<<<8192, 256, 0, stream>>>(out, ln3s, ln3b, XLN);
    gemm128d_k<2, u16, 0><<<dim3(32, 64), 256, 0, stream>>>(XLN, w1t, b1, nullptr, HML, 8192, 4096, 1024, 0);
    gemm128d_k<3, float, 0><<<dim3(8, 64), 256, 0, stream>>>(HML, w2t, b2, out, out, 8192, 1024, 4096, 0);
    return;
  }

  // ---------- per-batch fallback (~36 MB) ----------
  const size_t SLC = (size_t)LT_ * D_;
  u16* wT  = (u16*)alloc((size_t)1024 * 1024 * 2);
  u16* XLN = (u16*)alloc(SLC * 2);
  u16* Qb  = (u16*)alloc(SLC * 2);
  u16* Kb  = (u16*)alloc(SLC * 2);
  u16* Vb  = (u16*)alloc(SLC * 2);
  u16* KSb = (u16*)alloc(SLC * 2);
  u16* VSb = (u16*)alloc(SLC * 2);
  u16* Ob  = (u16*)alloc(SLC * 2);
  u16* Hc  = (u16*)alloc(SLC * 2);
  u16* Eb  = (u16*)alloc((size_t)LE_ * D_ * 2);
  float* KREP = (float*)alloc((size_t)NB_ * 1024 * 4);
  float* Pm = (float*)alloc((size_t)H_ * NB_ * NB_ * 4);

  auto T = [&](const float* src, int rs) {
    transpose_k<<<dim3(32, 32), 256, 0, stream>>>(src, wT, 1024, rs);
  };

  for (int b = 0; b < B_; ++b) {
    const float* tgt_b = targets + (size_t)b * SLC;
    const float* enc_b = encoded + (size_t)b * LE_ * D_;
    float* out_b = out + (size_t)b * SLC;

    ln_k<<<2048, 256, 0, stream>>>(tgt_b, ln1s, ln1b, XLN);
    T(wq1, 1024);
    gemm_k<0, u16, 0><<<dim3(8, 16), 256, 0, stream>>>(XLN, wT, nullptr, nullptr, Qb, 2048, 1024, 1024, 0);
    T(wk1, 1024);
    gemm_k<0, u16, 0><<<dim3(8, 16), 256, 0, stream>>>(XLN, wT, nullptr, nullptr, Kb, 2048, 1024, 1024, 0);
    T(wv1, 1024);
    gemm_k<0, u16, 0><<<dim3(8, 16), 256, 0, stream>>>(XLN, wT, nullptr, nullptr, Vb, 2048, 1024, 1024, 0);
    krep_k<<<64, 256, 0, stream>>>(Kb, KREP);
    sinkhorn_k<<<16, 256, 0, stream>>>(KREP, wsort, Pm);
    sortmix_k<<<1024, 256, 0, stream>>>(Pm, Kb, Vb, KSb, VSb);
    attn_mfma_k<0><<<256, 256, 0, stream>>>(Qb, Kb, Vb, KSb, VSb, Ob);
    T(wo1, 1024);
    gemm_k<1, float, 0><<<dim3(8, 16), 256, 0, stream>>>(Ob, wT, nullptr, tgt_b, out_b, 2048, 1024, 1024, 0);
    ln_k<<<2048, 256, 0, stream>>>(out_b, ln2s, ln2b, XLN);
    conv_k<<<1024, 256, 0, stream>>>(enc_b, Eb);
    T(wq2, 1024);
    gemm_k<0, u16, 0><<<dim3(8, 16), 256, 0, stream>>>(XLN, wT, nullptr, nullptr, Qb, 2048, 1024, 1024, 0);
    T(wk2, 1024);
    gemm_k<0, u16, 0><<<dim3(8, 8), 256, 0, stream>>>(Eb, wT, nullptr, nullptr, Kb, 1024, 1024, 1024, 0);
    T(wv2, 1024);
    gemm_k<0, u16, 0><<<dim3(8, 8), 256, 0, stream>>>(Eb, wT, nullptr, nullptr, Vb, 1024, 1024, 1024, 0);
    attn_mfma_k<1><<<256, 256, 0, stream>>>(Qb, Kb, Vb, nullptr, nullptr, Ob);
    T(wo2, 1024);
    gemm_k<1, float, 0><<<dim3(8, 16), 256, 0, stream>>>(Ob, wT, nullptr, out_b, out_b, 2048, 1024, 1024, 0);
    ln_k<<<2048, 256, 0, stream>>>(out_b, ln3s, ln3b, XLN);
    for (int c = 0; c < 4; ++c) {
      T(w1 + (size_t)c * 1024, 4096);
      gemm_k<2, u16, 0><<<dim3(8, 16), 256, 0, stream>>>(XLN, wT, b1 + c * 1024, nullptr, Hc,
                                                         2048, 1024, 1024, 0);
      T(w2 + (size_t)c * 1024 * 1024, 1024);
      if (c < 3)
        gemm_k<1, float, 0><<<dim3(8, 16), 256, 0, stream>>>(Hc, wT, nullptr, out_b, out_b,
                                                             2048, 1024, 1024, 0);
      else
        gemm_k<3, float, 0><<<dim3(8, 16), 256, 0, stream>>>(Hc, wT, b2, out_b, out_b,
                                                             2048, 1024, 1024, 0);
    }
  }
}

// Round 13
// 761.882 us; speedup vs baseline: 1.0094x; 1.0094x over previous
//
#include <hip/hip_runtime.h>

typedef unsigned short u16;
typedef unsigned int u32;
typedef __attribute__((ext_vector_type(8))) short short8;
typedef __attribute__((ext_vector_type(4))) short short4_t;
typedef __attribute__((ext_vector_type(4))) float float4_t;

#define B_ 4
#define LT_ 2048
#define LE_ 1024
#define D_ 1024
#define H_ 16
#define HD_ 64
#define NB_ 16
#define BS_ 128
#define M_ 4096
#define SCALE_ 0.125f

typedef __attribute__((address_space(1))) const void gas_t;
typedef __attribute__((address_space(3))) void las_t;

__device__ __forceinline__ float b2f(u16 u) {
  union { unsigned int i; float f; } v; v.i = ((unsigned int)u) << 16; return v.f;
}
__device__ __forceinline__ u16 f2b(float f) {
  union { float f; unsigned int i; } v; v.f = f;
  unsigned int x = v.i;
  return (u16)((x + 0x7fffu + ((x >> 16) & 1u)) >> 16);
}
__device__ __forceinline__ float gelu_f(float u) {
  // tanh-gelu via __expf: tanh(t) = 1 - 2/(exp(2t)+1)
  float t = 0.7978845608028654f * (u + 0.044715f * u * u * u);
  float th = 1.f - 2.f / (__expf(2.f * t) + 1.f);
  return 0.5f * u * (1.f + th);
}
__device__ __forceinline__ void store_val(u16* p, float x) { *p = f2b(x); }
__device__ __forceinline__ void store_val(float* p, float x) { *p = x; }

// ---------------- fp32 -> bf16 convert ----------------
__global__ __launch_bounds__(256)
void conv_k(const float* __restrict__ in, u16* __restrict__ out) {
  int i = (blockIdx.x * 256 + threadIdx.x) * 4;
  float4_t v = *(const float4_t*)(in + i);
  short4_t o;
  o[0] = (short)f2b(v[0]); o[1] = (short)f2b(v[1]);
  o[2] = (short)f2b(v[2]); o[3] = (short)f2b(v[3]);
  *(short4_t*)(out + i) = o;
}

// ---------------- transpose fp32 [R,Csub] (row stride) -> bf16 [Csub,R] ----------------
// (kept for the per-batch fallback path)
__global__ __launch_bounds__(256)
void transpose_k(const float* __restrict__ in, u16* __restrict__ out, int R, int rstride) {
  __shared__ u16 tile[32][33];
  int bx = blockIdx.x * 32, by = blockIdx.y * 32;
  int tx = threadIdx.x & 31, ty = threadIdx.x >> 5;
  #pragma unroll
  for (int y = ty; y < 32; y += 8)
    tile[y][tx] = f2b(in[(size_t)(by + y) * rstride + bx + tx]);
  __syncthreads();
  #pragma unroll
  for (int y = ty; y < 32; y += 8)
    out[(size_t)(bx + y) * R + by + tx] = tile[tx][y];
}

// ---------------- fused multi-transpose (one launch for all weight transposes) ----------
#define NJOBS 10
struct TJobs {
  const float* src[NJOBS];
  u16* dst[NJOBS];
  int outR[NJOBS];    // out row stride
  int inS[NJOBS];     // in row stride
  int ntx[NJOBS];     // tiles along out-row direction
  int ntiles[NJOBS];  // total tiles for this job
};

__global__ __launch_bounds__(256)
void prep_k(TJobs J) {
  int t = blockIdx.x, j = 0;
  while (t >= J.ntiles[j]) { t -= J.ntiles[j]; ++j; }   // uniform per block, <=10 iters
  const float* in = J.src[j];
  u16* out = J.dst[j];
  const int R = J.outR[j], rstride = J.inS[j];
  const int bx = (t % J.ntx[j]) * 32, by = (t / J.ntx[j]) * 32;
  __shared__ u16 tile[32][33];
  int tx = threadIdx.x & 31, ty = threadIdx.x >> 5;
  #pragma unroll
  for (int y = ty; y < 32; y += 8)
    tile[y][tx] = f2b(in[(size_t)(by + y) * rstride + bx + tx]);
  __syncthreads();
  #pragma unroll
  for (int y = ty; y < 32; y += 8)
    out[(size_t)(bx + y) * R + by + tx] = tile[tx][y];
}

// ---------------- layernorm (rows of 1024): fp32 in -> bf16 out ----------------
__global__ __launch_bounds__(256)
void ln_k(const float* __restrict__ x, const float* __restrict__ sw,
          const float* __restrict__ bw, u16* __restrict__ out) {
  int row = blockIdx.x, tid = threadIdx.x;
  const float* xr = x + (size_t)row * 1024 + tid * 4;
  float4_t raw = *(const float4_t*)xr;
  float v0 = raw[0], v1 = raw[1], v2 = raw[2], v3 = raw[3];
  float sum = v0 + v1 + v2 + v3;
  #pragma unroll
  for (int off = 32; off > 0; off >>= 1) sum += __shfl_down(sum, off, 64);
  __shared__ float sA[4], sB[4];
  int w = tid >> 6;
  if ((tid & 63) == 0) sA[w] = sum;
  __syncthreads();
  float mu = (sA[0] + sA[1] + sA[2] + sA[3]) * (1.f / 1024.f);
  float d0 = v0 - mu, d1 = v1 - mu, d2 = v2 - mu, d3 = v3 - mu;
  float s2 = d0 * d0 + d1 * d1 + d2 * d2 + d3 * d3;
  #pragma unroll
  for (int off = 32; off > 0; off >>= 1) s2 += __shfl_down(s2, off, 64);
  if ((tid & 63) == 0) sB[w] = s2;
  __syncthreads();
  float inv = rsqrtf((sB[0] + sB[1] + sB[2] + sB[3]) * (1.f / 1024.f) + 1e-6f);
  float4_t sv = *(const float4_t*)(sw + tid * 4);
  float4_t bv = *(const float4_t*)(bw + tid * 4);
  short4_t ov;
  ov[0] = (short)f2b(d0 * inv * sv[0] + bv[0]);
  ov[1] = (short)f2b(d1 * inv * sv[1] + bv[1]);
  ov[2] = (short)f2b(d2 * inv * sv[2] + bv[2]);
  ov[3] = (short)f2b(d3 * inv * sv[3] + bv[3]);
  *(short4_t*)(out + (size_t)row * 1024 + tid * 4) = ov;
}

// ---------------- MFMA GEMM (m97 structure, 2-barrier): fallback path only ------------
template<int EPI, typename TC, int SPLIT>
__global__ __launch_bounds__(256)
void gemm_k(const u16* __restrict__ A, const u16* __restrict__ Bt,
            const float* __restrict__ bias, const float* __restrict__ res,
            TC* __restrict__ C, int M, int N, int K, size_t cstride) {
  __shared__ __align__(16) u16 lA[128 * 32];
  __shared__ __align__(16) u16 lB[128 * 32];
  const int gx = gridDim.x;
  int lin = blockIdx.y * gx + blockIdx.x;
  const int nwg = gx * gridDim.y;
  if (!(nwg & 7)) {                    // all our grids are %8==0
    const int chunk = nwg >> 3;
    lin = (lin & 7) * chunk + (lin >> 3);
  }
  const int bn = (lin % gx) * 128;
  const int bm = (lin / gx) * 128;
  const int tid = threadIdx.x;
  const int lane = tid & 63;
  const int wave = tid >> 6;
  const int wy = wave >> 1, wx = wave & 1;
  const int quad = lane >> 4, l16 = lane & 15;

  float4_t acc[4][4];
  float4_t zz = {0.f, 0.f, 0.f, 0.f};
  #pragma unroll
  for (int i = 0; i < 4; ++i)
    #pragma unroll
    for (int j = 0; j < 4; ++j) acc[i][j] = zz;

  const int r0 = tid >> 2, kc0 = (tid & 3) * 8;       // u=0 chunk
  const u16* gA0 = A + (size_t)(bm + r0) * K + kc0;
  const u16* gA1 = A + (size_t)(bm + 64 + r0) * K + kc0;
  const u16* gB0 = Bt + (size_t)(bn + r0) * K + kc0;
  const u16* gB1 = Bt + (size_t)(bn + 64 + r0) * K + kc0;
  u16* lA0 = &lA[tid * 8];
  u16* lA1 = &lA[(tid + 256) * 8];
  u16* lB0 = &lB[tid * 8];
  u16* lB1 = &lB[(tid + 256) * 8];

  for (int k0 = 0; k0 < K; k0 += 32) {
    __syncthreads();
    __builtin_amdgcn_global_load_lds((gas_t*)(gA0 + k0), (las_t*)lA0, 16, 0, 0);
    __builtin_amdgcn_global_load_lds((gas_t*)(gA1 + k0), (las_t*)lA1, 16, 0, 0);
    __builtin_amdgcn_global_load_lds((gas_t*)(gB0 + k0), (las_t*)lB0, 16, 0, 0);
    __builtin_amdgcn_global_load_lds((gas_t*)(gB1 + k0), (las_t*)lB1, 16, 0, 0);
    __syncthreads();
    short8 af[4], bfr[4];
    #pragma unroll
    for (int i = 0; i < 4; ++i)
      af[i] = *(const short8*)&lA[(wy * 64 + i * 16 + l16) * 32 + quad * 8];
    #pragma unroll
    for (int j = 0; j < 4; ++j)
      bfr[j] = *(const short8*)&lB[(wx * 64 + j * 16 + l16) * 32 + quad * 8];
    #pragma unroll
    for (int i = 0; i < 4; ++i)
      #pragma unroll
      for (int j = 0; j < 4; ++j)
        acc[i][j] = __builtin_amdgcn_mfma_f32_16x16x32_bf16(af[i], bfr[j], acc[i][j], 0, 0, 0);
  }

  #pragma unroll
  for (int i = 0; i < 4; ++i) {
    int row = bm + wy * 64 + i * 16 + quad * 4;
    #pragma unroll
    for (int j = 0; j < 4; ++j) {
      int col = bn + wx * 64 + j * 16 + l16;
      TC* Cb = SPLIT ? (C + (size_t)(col >> 10) * cstride) : C;
      int ccol = SPLIT ? (col & 1023) : col;
      int cn = SPLIT ? 1024 : N;
      #pragma unroll
      for (int v = 0; v < 4; ++v) {
        float x = acc[i][j][v];
        size_t idx = (size_t)(row + v) * cn + ccol;
        if (EPI == 1) {
          x += res[idx];
        } else if (EPI == 2) {
          x = gelu_f(x + bias[col]);
        } else if (EPI == 3) {
          x += bias[col] + res[idx];
        }
        store_val(&Cb[idx], x);
      }
    }
  }
}

// ---------------- 128x128 deep-pipelined GEMM (counted-vmcnt, 2 blocks/CU) ----------
// Round-12 swizzle used row bits 0-1 (l16&3): bit 0 aliases with the intrinsic
// 4*(row&1) bank-group offset -> still 4 groups x4 lanes, counter unchanged
// (saturated 2^23). FIX: XOR with row bits 1-2 ((l16>>1)&3) exactly like the
// 0-conflict gemm256_k: groups = 4*(row&1) + quad^((row>>1)&3) covers all 8
// bank-groups x2 lanes = free. Stage pre-swizzles global col with the same
// bits; +64-row chunk preserves (row>>1)&3 (64/2 mod 4 = 0).
template<int EPI, typename TC, int SPLIT>
__global__ __launch_bounds__(256, 2)
void gemm128d_k(const u16* __restrict__ A, const u16* __restrict__ Bt,
                const float* __restrict__ bias, const float* __restrict__ res,
                TC* __restrict__ C, int M, int N, int K, size_t cstride) {
  __shared__ __align__(16) u16 lA[4][128 * 32];
  __shared__ __align__(16) u16 lB[4][128 * 32];
  const int gx = gridDim.x;
  int lin = blockIdx.y * gx + blockIdx.x;
  const int nwg = gx * gridDim.y;
  if (!(nwg & 7)) {
    const int chunk = nwg >> 3;
    lin = (lin & 7) * chunk + (lin >> 3);
  }
  const int bn = (lin % gx) * 128;
  const int bm = (lin / gx) * 128;
  const int tid = threadIdx.x;
  const int lane = tid & 63;
  const int wave = tid >> 6;
  const int wy = wave >> 1, wx = wave & 1;
  const int quad = lane >> 4, l16 = lane & 15;
  const int slo = (quad ^ ((l16 >> 1) & 3)) * 8;  // swizzled slot (row bits 1-2)

  float4_t acc[4][4];
  float4_t zz = {0.f, 0.f, 0.f, 0.f};
  #pragma unroll
  for (int i = 0; i < 4; ++i)
    #pragma unroll
    for (int j = 0; j < 4; ++j) acc[i][j] = zz;

  const int r0 = tid >> 2;
  const int kc0 = ((tid & 3) ^ ((r0 >> 1) & 3)) * 8;  // pre-swizzled global k-col
  const u16* gA0 = A + (size_t)(bm + r0) * K + kc0;
  const u16* gA1 = A + (size_t)(bm + 64 + r0) * K + kc0;
  const u16* gB0 = Bt + (size_t)(bn + r0) * K + kc0;
  const u16* gB1 = Bt + (size_t)(bn + 64 + r0) * K + kc0;
  const int NT = K >> 5;

  #define STAGE128(TT, BUF)                                                      \
    {                                                                            \
      int kk_ = (TT) * 32;                                                       \
      __builtin_amdgcn_global_load_lds((gas_t*)(gA0 + kk_),                      \
          (las_t*)&lA[BUF][tid * 8], 16, 0, 0);                                  \
      __builtin_amdgcn_global_load_lds((gas_t*)(gA1 + kk_),                      \
          (las_t*)&lA[BUF][(tid + 256) * 8], 16, 0, 0);                          \
      __builtin_amdgcn_global_load_lds((gas_t*)(gB0 + kk_),                      \
          (las_t*)&lB[BUF][tid * 8], 16, 0, 0);                                  \
      __builtin_amdgcn_global_load_lds((gas_t*)(gB1 + kk_),                      \
          (las_t*)&lB[BUF][(tid + 256) * 8], 16, 0, 0);                          \
    }

  STAGE128(0, 0)
  STAGE128(1, 1)
  STAGE128(2, 2)

  for (int t = 0; t < NT; ++t) {
    asm volatile("s_waitcnt vmcnt(8)" ::: "memory");   // tile t resident; t+1,t+2 in flight
    __builtin_amdgcn_s_barrier();
    __builtin_amdgcn_sched_barrier(0);
    int ts = t + 3; if (ts > NT - 1) ts = NT - 1;      // tail: dummy re-stage, dead buffer
    STAGE128(ts, (t + 3) & 3)
    const u16* bufA = &lA[t & 3][0];
    const u16* bufB = &lB[t & 3][0];
    short8 af[4], bfr[4];
    #pragma unroll
    for (int i = 0; i < 4; ++i)
      af[i] = *(const short8*)&bufA[(wy * 64 + i * 16 + l16) * 32 + slo];
    #pragma unroll
    for (int j = 0; j < 4; ++j)
      bfr[j] = *(const short8*)&bufB[(wx * 64 + j * 16 + l16) * 32 + slo];
    __builtin_amdgcn_s_setprio(1);
    #pragma unroll
    for (int i = 0; i < 4; ++i)
      #pragma unroll
      for (int j = 0; j < 4; ++j)
        acc[i][j] = __builtin_amdgcn_mfma_f32_16x16x32_bf16(af[i], bfr[j], acc[i][j], 0, 0, 0);
    __builtin_amdgcn_s_setprio(0);
  }
  #undef STAGE128

  #pragma unroll
  for (int i = 0; i < 4; ++i) {
    int row = bm + wy * 64 + i * 16 + quad * 4;
    #pragma unroll
    for (int j = 0; j < 4; ++j) {
      int col = bn + wx * 64 + j * 16 + l16;
      TC* Cb = SPLIT ? (C + (size_t)(col >> 10) * cstride) : C;
      int ccol = SPLIT ? (col & 1023) : col;
      int cn = SPLIT ? 1024 : N;
      #pragma unroll
      for (int v = 0; v < 4; ++v) {
        float x = acc[i][j][v];
        size_t idx = (size_t)(row + v) * cn + ccol;
        if (EPI == 1) {
          x += res[idx];
        } else if (EPI == 2) {
          x = gelu_f(x + bias[col]);
        } else if (EPI == 3) {
          x += bias[col] + res[idx];
        }
        store_val(&Cb[idx], x);
      }
    }
  }
}

// ---------------- 256x256 deep-pipelined MFMA GEMM (counted-vmcnt) -----------------
// Retained for reference/fallback (1 block/CU quantization at small grids).
template<int EPI, typename TC, int SPLIT>
__global__ __launch_bounds__(512, 2)
void gemm256_k(const u16* __restrict__ A, const u16* __restrict__ Bt,
               const float* __restrict__ bias, const float* __restrict__ res,
               TC* __restrict__ C, int M, int N, int K, size_t cstride) {
  __shared__ __align__(16) u16 lA[4][256 * 32];
  __shared__ __align__(16) u16 lB[4][256 * 32];
  const int gx = gridDim.x;
  int lin = blockIdx.y * gx + blockIdx.x;
  const int nwg = gx * gridDim.y;
  if (!(nwg & 7)) {
    const int chunk = nwg >> 3;
    lin = (lin & 7) * chunk + (lin >> 3);
  }
  const int bn = (lin % gx) * 256;
  const int bm = (lin / gx) * 256;
  const int tid = threadIdx.x;
  const int lane = tid & 63;
  const int wave = tid >> 6;
  const int wy = wave >> 2, wx = wave & 3;        // 2 x 4 waves
  const int quad = lane >> 4, l16 = lane & 15;
  const int slo = ((quad ^ ((l16 >> 1) & 3)) << 4);  // swizzled 16B slot (bytes)

  int lrow[2], kcs[2];
  #pragma unroll
  for (int u = 0; u < 2; ++u) {
    int p = (tid + u * 512) * 16;
    int lg = p ^ (((p >> 7) & 3) << 4);
    lrow[u] = lg >> 6;
    kcs[u] = (lg & 63) >> 1;
  }
  const u16* gA[2]; const u16* gB[2];
  #pragma unroll
  for (int u = 0; u < 2; ++u) {
    gA[u] = A + (size_t)(bm + lrow[u]) * K + kcs[u];
    gB[u] = Bt + (size_t)(bn + lrow[u]) * K + kcs[u];
  }
  const int NT = K >> 5;

  float4_t acc[8][4];
  float4_t zz = {0.f, 0.f, 0.f, 0.f};
  #pragma unroll
  for (int i = 0; i < 8; ++i)
    #pragma unroll
    for (int j = 0; j < 4; ++j) acc[i][j] = zz;

  #define STAGE256(TT, BUF)                                                      \
    {                                                                            \
      int kk_ = (TT) * 32;                                                       \
      __builtin_amdgcn_global_load_lds((gas_t*)(gA[0] + kk_),                    \
          (las_t*)((char*)&lA[BUF][0] + tid * 16), 16, 0, 0);                    \
      __builtin_amdgcn_global_load_lds((gas_t*)(gA[1] + kk_),                    \
          (las_t*)((char*)&lA[BUF][0] + (tid + 512) * 16), 16, 0, 0);            \
      __builtin_amdgcn_global_load_lds((gas_t*)(gB[0] + kk_),                    \
          (las_t*)((char*)&lB[BUF][0] + tid * 16), 16, 0, 0);                    \
      __builtin_amdgcn_global_load_lds((gas_t*)(gB[1] + kk_),                    \
          (las_t*)((char*)&lB[BUF][0] + (tid + 512) * 16), 16, 0, 0);            \
    }

  STAGE256(0, 0)
  STAGE256(1, 1)
  STAGE256(2, 2)

  for (int t = 0; t < NT; ++t) {
    asm volatile("s_waitcnt vmcnt(8)" ::: "memory");   // tile t resident; t+1,t+2 in flight
    __builtin_amdgcn_s_barrier();
    __builtin_amdgcn_sched_barrier(0);
    int ts = t + 3; if (ts > NT - 1) ts = NT - 1;      // tail: dummy re-stage, dead buffer
    STAGE256(ts, (t + 3) & 3)
    const char* bufA = (const char*)&lA[t & 3][0];
    const char* bufB = (const char*)&lB[t & 3][0];
    short8 af[8], bf[4];
    #pragma unroll
    for (int i = 0; i < 8; ++i)
      af[i] = *(const short8*)(bufA + (wy * 128 + i * 16 + l16) * 64 + slo);
    #pragma unroll
    for (int j = 0; j < 4; ++j)
      bf[j] = *(const short8*)(bufB + (wx * 64 + j * 16 + l16) * 64 + slo);
    __builtin_amdgcn_s_setprio(1);
    #pragma unroll
    for (int i = 0; i < 8; ++i)
      #pragma unroll
      for (int j = 0; j < 4; ++j)
        acc[i][j] = __builtin_amdgcn_mfma_f32_16x16x32_bf16(af[i], bf[j], acc[i][j], 0, 0, 0);
    __builtin_amdgcn_s_setprio(0);
  }
  #undef STAGE256

  #pragma unroll
  for (int i = 0; i < 8; ++i) {
    int row = bm + wy * 128 + i * 16 + quad * 4;
    #pragma unroll
    for (int j = 0; j < 4; ++j) {
      int col = bn + wx * 64 + j * 16 + l16;
      TC* Cb = SPLIT ? (C + (size_t)(col >> 10) * cstride) : C;
      int ccol = SPLIT ? (col & 1023) : col;
      int cn = SPLIT ? 1024 : N;
      #pragma unroll
      for (int v = 0; v < 4; ++v) {
        float x = acc[i][j][v];
        size_t idx = (size_t)(row + v) * cn + ccol;
        if (EPI == 1) {
          x += res[idx];
        } else if (EPI == 2) {
          x = gelu_f(x + bias[col]);
        } else if (EPI == 3) {
          x += bias[col] + res[idx];
        }
        store_val(&Cb[idx], x);
      }
    }
  }
}

// ---------------- krep: sum k over block rows (b decoded from idx) ----------------
__global__ __launch_bounds__(256)
void krep_k(const u16* __restrict__ K1, float* __restrict__ krep) {
  int idx = blockIdx.x * 256 + threadIdx.x;   // (#batches)*NB*1024
  int col = idx & 1023;
  int bn = idx >> 10;
  const u16* p = K1 + (size_t)bn * 128 * 1024 + col;
  float s = 0.f;
  for (int i = 0; i < 128; ++i) s += b2f(p[(size_t)i * 1024]);
  krep[idx] = s;
}

// ---------------- sinkhorn: grid = (#batches)*H, one (b,h) each ----------------
__global__ __launch_bounds__(256)
void sinkhorn_k(const float* __restrict__ krep, const float* __restrict__ wsort,
                float* __restrict__ P) {
  int bh = blockIdx.x;
  int b = bh >> 4, h = bh & 15;
  int t = threadIdx.x;
  int i = t >> 4, j = t & 15;
  __shared__ float la[16][17];
  __shared__ float red[16];
  float acc = 0.f;
  const float* kr = krep + ((size_t)b * 16 + i) * 1024 + h * 64;
  const float* ws = wsort + (size_t)h * 64 * 16 + j;
  for (int k = 0; k < 64; ++k) acc += kr[k] * ws[k * 16];
  la[i][j] = (j <= i) ? acc : -1e9f;
  __syncthreads();
  for (int it = 0; it < 5; ++it) {
    if (t < 16) {
      float m = -1e30f;
      for (int jj = 0; jj < 16; ++jj) m = fmaxf(m, la[t][jj]);
      float s = 0.f;
      for (int jj = 0; jj < 16; ++jj) s += __expf(la[t][jj] - m);
      red[t] = m + __logf(s);
    }
    __syncthreads();
    la[i][j] = (j <= i) ? la[i][j] - red[i] : -1e9f;
    __syncthreads();
    if (t < 16) {
      float m = -1e30f;
      for (int ii = 0; ii < 16; ++ii) m = fmaxf(m, la[ii][t]);
      float s = 0.f;
      for (int ii = 0; ii < 16; ++ii) s += __expf(la[ii][t] - m);
      red[t] = m + __logf(s);
    }
    __syncthreads();
    la[i][j] = (j <= i) ? la[i][j] - red[j] : -1e9f;
    __syncthreads();
  }
  P[((size_t)bh * 16 + i) * 16 + j] = __expf(la[i][j]);
}

// ---------------- sorted block mix (b decoded from idx), short8 loads ----------------
__global__ __launch_bounds__(256)
void sortmix_k(const float* __restrict__ P, const u16* __restrict__ K1,
               const u16* __restrict__ V1, u16* __restrict__ KS,
               u16* __restrict__ VS) {
  int t = blockIdx.x * 256 + threadIdx.x;     // (#batches)*2048*128 (8 cols each)
  int col = (t & 127) * 8;
  int rest = t >> 7;                          // b*2048 + i*128 + s
  int b = rest >> 11, is = rest & 2047, i = is >> 7, s = is & 127;
  int h = col >> 6;                           // 8-col chunk never straddles a head
  const float* Pr = P + (((size_t)(b * 16 + h)) * 16 + i) * 16;
  size_t base = ((size_t)(b * 2048 + s)) * 1024 + col;
  float ka[8] = {0, 0, 0, 0, 0, 0, 0, 0}, va[8] = {0, 0, 0, 0, 0, 0, 0, 0};
  for (int j = 0; j <= i; ++j) {   // P[i][j]==0 for j>i (causal mask)
    float p = Pr[j];
    short8 kk = *(const short8*)&K1[base + (size_t)j * 131072];
    short8 vv = *(const short8*)&V1[base + (size_t)j * 131072];
    #pragma unroll
    for (int e = 0; e < 8; ++e) {
      ka[e] += p * b2f((u16)kk[e]);
      va[e] += p * b2f((u16)vv[e]);
    }
  }
  size_t ob = ((size_t)(b * 2048 + i * 128 + s)) * 1024 + col;
  short8 ok, ov;
  #pragma unroll
  for (int e = 0; e < 8; ++e) { ok[e] = (short)f2b(ka[e]); ov[e] = (short)f2b(va[e]); }
  *(short8*)&KS[ob] = ok;
  *(short8*)&VS[ob] = ov;
}

// ---------------- MFMA flash attention (conflict-free LDS redesign) ----------------
// Verified correct on HW rounds 8-12. kls XOR-swizzled, V transposed via 2-pass
// LDS (b128 writes), P in registers via shfl-assembled PV A-fragments.
template<int CROSS>
__global__ __launch_bounds__(256)
void attn_mfma_k(const u16* __restrict__ Q, const u16* __restrict__ Ka,
                 const u16* __restrict__ Va, const u16* __restrict__ Kb2,
                 const u16* __restrict__ Vb2, u16* __restrict__ O) {
  __shared__ __align__(16) u16 kls[128 * 64];
  __shared__ __align__(16) u16 vlin[128 * 64];
  __shared__ __align__(16) u16 vtls[64 * 128];
  int blk = blockIdx.x;
  {
    int nwg = gridDim.x;
    if (!(nwg & 7)) { int ch = nwg >> 3; blk = (blk & 7) * ch + (blk >> 3); }
  }
  const int n = blk & 15, h = (blk >> 4) & 15, b = blk >> 8;
  const int tid = threadIdx.x, lane = tid & 63, wv = tid >> 6;
  const int quad = lane >> 4, l16 = lane & 15;
  const int m0 = wv * 32;
  const size_t qrowbase = (size_t)b * 2048 + n * 128;

  short8 qa[2][2];
  #pragma unroll
  for (int qi = 0; qi < 2; ++qi)
    #pragma unroll
    for (int ks = 0; ks < 2; ++ks)
      qa[qi][ks] = *(const short8*)&Q[(qrowbase + m0 + qi * 16 + l16) * 1024 +
                                      h * 64 + ks * 32 + quad * 8];

  float4_t acc_o[2][4];
  float mrow[2], lrow[2];
  #pragma unroll
  for (int mi = 0; mi < 2; ++mi) {
    #pragma unroll
    for (int dn = 0; dn < 4; ++dn) acc_o[mi][dn] = {0.f, 0.f, 0.f, 0.f};
    mrow[mi] = -1e30f; lrow[mi] = 0.f;
  }

  const int NT = CROSS ? 8 : 2;
  for (int t = 0; t < NT; ++t) {
    const u16 *Kg, *Vg;
    bool causal = false;
    if (CROSS) {
      size_t kb = ((size_t)b * 1024 + t * 128) * 1024 + h * 64;
      Kg = Ka + kb; Vg = Va + kb;
    } else if (t == 0) {
      size_t kb = qrowbase * 1024 + h * 64;
      Kg = Ka + kb; Vg = Va + kb; causal = true;
    } else {
      size_t kb = qrowbase * 1024 + h * 64;
      Kg = Kb2 + kb; Vg = Vb2 + kb;
    }
    // ---- stage K (swizzled) + V (linear) ----
    #pragma unroll
    for (int i = 0; i < 4; ++i) {
      int c = tid + i * 256;
      int row = c >> 3, slot = c & 7, dd = slot * 8;
      short8 kv8 = *(const short8*)&Kg[(size_t)row * 1024 + dd];
      *(short8*)&kls[row * 64 + ((slot ^ (row & 7)) * 8)] = kv8;
      short8 vv8 = *(const short8*)&Vg[(size_t)row * 1024 + dd];
      *(short8*)&vlin[row * 64 + dd] = vv8;
    }
    __syncthreads();                       // bar1: staging visible

    // ---- transpose vlin -> vtls (conflict-free) ----
    #pragma unroll
    for (int ii = 0; ii < 4; ++ii) {
      int d = tid & 63;
      int kvg = (tid >> 6) * 4 + ii;       // 0..15
      union { short8 s8; u16 us[8]; } tt;
      #pragma unroll
      for (int j = 0; j < 8; ++j)
        tt.us[j] = vlin[(kvg * 8 + j) * 64 + d];
      int slotp = (kvg & 8) | ((kvg ^ (d & 7)) & 7);
      *(short8*)&vtls[d * 128 + slotp * 8] = tt.s8;
    }

    // ---- QK^T, swapped operands: s[qi][nj] holds S^T (kv on quad*4+v, q on l16)
    float4_t s[2][8];
    #pragma unroll
    for (int qi = 0; qi < 2; ++qi)
      #pragma unroll
      for (int nj = 0; nj < 8; ++nj) s[qi][nj] = {0.f, 0.f, 0.f, 0.f};
    #pragma unroll
    for (int nj = 0; nj < 8; ++nj) {
      int r = nj * 16 + l16;
      short8 k0 = *(const short8*)&kls[r * 64 + ((quad ^ (l16 & 7)) * 8)];
      short8 k1 = *(const short8*)&kls[r * 64 + (((4 + quad) ^ (l16 & 7)) * 8)];
      #pragma unroll
      for (int qi = 0; qi < 2; ++qi) {
        s[qi][nj] = __builtin_amdgcn_mfma_f32_16x16x32_bf16(k0, qa[qi][0], s[qi][nj], 0, 0, 0);
        s[qi][nj] = __builtin_amdgcn_mfma_f32_16x16x32_bf16(k1, qa[qi][1], s[qi][nj], 0, 0, 0);
      }
    }

    // ---- lane-local online softmax; P kept in registers as bf16 pairs
    float crv[2];
    u32 p01[2][8], p23[2][8];
    #pragma unroll
    for (int qi = 0; qi < 2; ++qi) {
      const int qrow = m0 + qi * 16 + l16;     // block-local q row
      float mx = -1e30f;
      #pragma unroll
      for (int nj = 0; nj < 8; ++nj)
        #pragma unroll
        for (int v = 0; v < 4; ++v) {
          float x = s[qi][nj][v] * SCALE_;
          if (causal && (nj * 16 + quad * 4 + v > qrow)) x = -1e30f;
          s[qi][nj][v] = x;
          mx = fmaxf(mx, x);
        }
      mx = fmaxf(mx, __shfl_xor(mx, 16, 64));
      mx = fmaxf(mx, __shfl_xor(mx, 32, 64));
      float mn = fmaxf(mrow[qi], mx);
      crv[qi] = __expf(mrow[qi] - mn);
      mrow[qi] = mn;
      float rs = 0.f;
      #pragma unroll
      for (int nj = 0; nj < 8; ++nj)
        #pragma unroll
        for (int v = 0; v < 4; ++v) {
          float p = __expf(s[qi][nj][v] - mn);
          s[qi][nj][v] = p;
          rs += p;
        }
      rs += __shfl_xor(rs, 16, 64);
      rs += __shfl_xor(rs, 32, 64);
      lrow[qi] = lrow[qi] * crv[qi] + rs;
      #pragma unroll
      for (int nj = 0; nj < 8; ++nj) {
        p01[qi][nj] = (u32)f2b(s[qi][nj][0]) | ((u32)f2b(s[qi][nj][1]) << 16);
        p23[qi][nj] = (u32)f2b(s[qi][nj][2]) | ((u32)f2b(s[qi][nj][3]) << 16);
      }
    }
    // rescale accumulator: acc_o rows are q = m0 + mi*16 + quad*4 + v,
    // whose cr lives in lane l16 = quad*4+v (any quad; pick same quad).
    #pragma unroll
    for (int mi = 0; mi < 2; ++mi)
      #pragma unroll
      for (int v = 0; v < 4; ++v) {
        float c = __shfl(crv[mi], quad * 20 + v, 64);
        #pragma unroll
        for (int dn = 0; dn < 4; ++dn) acc_o[mi][dn][v] *= c;
      }

    __syncthreads();                       // bar2: vtls transpose visible

    // ---- PV: A-frag assembled in-register via shfl; B-frag from swizzled vtls
    const int src0 = (quad & 1) * 32 + l16;   // qs0*16 + l16
    const int src1 = src0 + 16;
    const bool hi = (quad >> 1) != 0;
    #pragma unroll
    for (int ks = 0; ks < 4; ++ks) {
      union { short8 s8; u32 u[4]; } au[2];
      #pragma unroll
      for (int qi = 0; qi < 2; ++qi) {
        u32 w0a = __shfl(p01[qi][2 * ks],     src0, 64);
        u32 w0b = __shfl(p01[qi][2 * ks + 1], src0, 64);
        u32 w1a = __shfl(p23[qi][2 * ks],     src0, 64);
        u32 w1b = __shfl(p23[qi][2 * ks + 1], src0, 64);
        u32 w2a = __shfl(p01[qi][2 * ks],     src1, 64);
        u32 w2b = __shfl(p01[qi][2 * ks + 1], src1, 64);
        u32 w3a = __shfl(p23[qi][2 * ks],     src1, 64);
        u32 w3b = __shfl(p23[qi][2 * ks + 1], src1, 64);
        au[qi].u[0] = hi ? w0b : w0a;
        au[qi].u[1] = hi ? w1b : w1a;
        au[qi].u[2] = hi ? w2b : w2a;
        au[qi].u[3] = hi ? w3b : w3a;
      }
      #pragma unroll
      for (int dn = 0; dn < 4; ++dn) {
        int dR = dn * 16 + l16;
        int sbase = ks * 4 + quad;
        int sp = (sbase & 8) | ((sbase ^ (l16 & 7)) & 7);
        short8 bv = *(const short8*)&vtls[dR * 128 + sp * 8];
        acc_o[0][dn] = __builtin_amdgcn_mfma_f32_16x16x32_bf16(au[0].s8, bv, acc_o[0][dn], 0, 0, 0);
        acc_o[1][dn] = __builtin_amdgcn_mfma_f32_16x16x32_bf16(au[1].s8, bv, acc_o[1][dn], 0, 0, 0);
      }
    }
  }
  #pragma unroll
  for (int mi = 0; mi < 2; ++mi) {
    float invl = 1.f / lrow[mi];
    #pragma unroll
    for (int v = 0; v < 4; ++v) {
      float inv = __shfl(invl, quad * 20 + v, 64);
      int rowl = m0 + mi * 16 + quad * 4 + v;
      #pragma unroll
      for (int dn = 0; dn < 4; ++dn)
        O[(qrowbase + rowl) * 1024 + h * 64 + dn * 16 + l16] =
            f2b(acc_o[mi][dn][v] * inv);
    }
  }
}

// ---------------- host ----------------
extern "C" void kernel_launch(void* const* d_in, const int* in_sizes, int n_in,
                              void* d_out, int out_size, void* d_ws, size_t ws_size,
                              hipStream_t stream) {
  const float* targets = (const float*)d_in[0];
  const float* encoded = (const float*)d_in[1];
  const float* ln1s = (const float*)d_in[2];
  const float* ln1b = (const float*)d_in[3];
  const float* ln2s = (const float*)d_in[4];
  const float* ln2b = (const float*)d_in[5];
  const float* ln3s = (const float*)d_in[6];
  const float* ln3b = (const float*)d_in[7];
  const float* wq1 = (const float*)d_in[8];
  const float* wk1 = (const float*)d_in[9];
  const float* wv1 = (const float*)d_in[10];
  const float* wo1 = (const float*)d_in[11];
  const float* wsort = (const float*)d_in[12];
  const float* wq2 = (const float*)d_in[13];
  const float* wk2 = (const float*)d_in[14];
  const float* wv2 = (const float*)d_in[15];
  const float* wo2 = (const float*)d_in[16];
  const float* w1 = (const float*)d_in[17];
  const float* b1 = (const float*)d_in[18];
  const float* w2 = (const float*)d_in[19];
  const float* b2 = (const float*)d_in[20];
  float* out = (float*)d_out;
  (void)in_sizes; (void)n_in; (void)out_size;

  char* ws = (char*)d_ws;
  size_t off = 0;
  auto alloc = [&](size_t n) -> char* {
    char* p = ws + off;
    off += (n + 255) & ~(size_t)255;
    return p;
  };

  const size_t NTD = (size_t)B_ * LT_ * D_;         // 8.4M elems
  const size_t NEED_BIG = (size_t)(8 * 2 + 8 + 8) * 1024 * 1024   // weights bf16
                        + (size_t)LE_ * B_ * D_ * 2                // Eb
                        + NTD * 2 * 7                              // XLN + 6 act
                        + (1u << 20);                              // small + slack

  if (ws_size >= NEED_BIG) {
    // ---------- whole-batch path ----------
    u16* wq1t = (u16*)alloc((size_t)1024 * 1024 * 2);
    u16* wk1t = (u16*)alloc((size_t)1024 * 1024 * 2);
    u16* wv1t = (u16*)alloc((size_t)1024 * 1024 * 2);
    u16* wo1t = (u16*)alloc((size_t)1024 * 1024 * 2);
    u16* wq2t = (u16*)alloc((size_t)1024 * 1024 * 2);
    u16* wk2t = (u16*)alloc((size_t)1024 * 1024 * 2);
    u16* wv2t = (u16*)alloc((size_t)1024 * 1024 * 2);
    u16* wo2t = (u16*)alloc((size_t)1024 * 1024 * 2);
    u16* w1t = (u16*)alloc((size_t)4096 * 1024 * 2);
    u16* w2t = (u16*)alloc((size_t)1024 * 4096 * 2);
    u16* Eb  = (u16*)alloc((size_t)B_ * LE_ * D_ * 2);
    u16* XLN = (u16*)alloc(NTD * 2);
    u16* Qb  = (u16*)alloc(NTD * 2);    // Qb..KSb (67.1MB contiguous) = MLP hidden
    u16* Kb  = (u16*)alloc(NTD * 2);
    u16* Vb  = (u16*)alloc(NTD * 2);
    u16* KSb = (u16*)alloc(NTD * 2);
    u16* VSb = (u16*)alloc(NTD * 2);
    u16* Ob  = (u16*)alloc(NTD * 2);
    float* KREP = (float*)alloc((size_t)B_ * NB_ * 1024 * 4);
    float* Pm = (float*)alloc((size_t)B_ * H_ * NB_ * NB_ * 4);
    u16* HML = Qb;

    // one fused launch for all 10 weight transposes
    TJobs J;
    const float* srcs[NJOBS] = {wq1, wk1, wv1, wo1, wq2, wk2, wv2, wo2, w1, w2};
    u16* dsts[NJOBS] = {wq1t, wk1t, wv1t, wo1t, wq2t, wk2t, wv2t, wo2t, w1t, w2t};
    int total = 0;
    for (int j = 0; j < NJOBS; ++j) {
      J.src[j] = srcs[j]; J.dst[j] = dsts[j];
      if (j < 8)      { J.outR[j] = 1024; J.inS[j] = 1024; J.ntx[j] = 32;  J.ntiles[j] = 1024; }
      else if (j == 8){ J.outR[j] = 1024; J.inS[j] = 4096; J.ntx[j] = 128; J.ntiles[j] = 4096; }
      else            { J.outR[j] = 4096; J.inS[j] = 1024; J.ntx[j] = 32;  J.ntiles[j] = 4096; }
      total += J.ntiles[j];
    }
    prep_k<<<total, 256, 0, stream>>>(J);
    conv_k<<<4096, 256, 0, stream>>>(encoded, Eb);

    ln_k<<<8192, 256, 0, stream>>>(targets, ln1s, ln1b, XLN);
    // fused QKV projection on 128^2 deep-pipelined kernel: 1536 blocks at
    // 2/CU = 3 exactly-full rounds
    gemm128d_k<0, u16, 1><<<dim3(24, 64), 256, 0, stream>>>(XLN, wq1t, nullptr, nullptr,
                                                            Qb, 8192, 3072, 1024, NTD);
    krep_k<<<256, 256, 0, stream>>>(Kb, KREP);
    sinkhorn_k<<<64, 256, 0, stream>>>(KREP, wsort, Pm);
    sortmix_k<<<4096, 256, 0, stream>>>(Pm, Kb, Vb, KSb, VSb);
    attn_mfma_k<0><<<1024, 256, 0, stream>>>(Qb, Kb, Vb, KSb, VSb, Ob);
    gemm128d_k<1, float, 0><<<dim3(8, 64), 256, 0, stream>>>(Ob, wo1t, nullptr, targets, out, 8192, 1024, 1024, 0);
    ln_k<<<8192, 256, 0, stream>>>(out, ln2s, ln2b, XLN);
    gemm128d_k<0, u16, 0><<<dim3(8, 64), 256, 0, stream>>>(XLN, wq2t, nullptr, nullptr, Qb, 8192, 1024, 1024, 0);
    // fused K2/V2 projection of encoded: Bt = [wk2t;wv2t] (N=2048), split -> Kb/Vb
    gemm128d_k<0, u16, 1><<<dim3(16, 32), 256, 0, stream>>>(Eb, wk2t, nullptr, nullptr, Kb, 4096, 2048, 1024, NTD);
    attn_mfma_k<1><<<1024, 256, 0, stream>>>(Qb, Kb, Vb, nullptr, nullptr, Ob);
    gemm128d_k<1, float, 0><<<dim3(8, 64), 256, 0, stream>>>(Ob, wo2t, nullptr, out, out, 8192, 1024, 1024, 0);
    ln_k<<<8192, 256, 0, stream>>>(out, ln3s, ln3b, XLN);
    gemm128d_k<2, u16, 0><<<dim3(32, 64), 256, 0, stream>>>(XLN, w1t, b1, nullptr, HML, 8192, 4096, 1024, 0);
    gemm128d_k<3, float, 0><<<dim3(8, 64), 256, 0, stream>>>(HML, w2t, b2, out, out, 8192, 1024, 4096, 0);
    return;
  }

  // ---------- per-batch fallback (~36 MB) ----------
  const size_t SLC = (size_t)LT_ * D_;
  u16* wT  = (u16*)alloc((size_t)1024 * 1024 * 2);
  u16* XLN = (u16*)alloc(SLC * 2);
  u16* Qb  = (u16*)alloc(SLC * 2);
  u16* Kb  = (u16*)alloc(SLC * 2);
  u16* Vb  = (u16*)alloc(SLC * 2);
  u16* KSb = (u16*)alloc(SLC * 2);
  u16* VSb = (u16*)alloc(SLC * 2);
  u16* Ob  = (u16*)alloc(SLC * 2);
  u16* Hc  = (u16*)alloc(SLC * 2);
  u16* Eb  = (u16*)alloc((size_t)LE_ * D_ * 2);
  float* KREP = (float*)alloc((size_t)NB_ * 1024 * 4);
  float* Pm = (float*)alloc((size_t)H_ * NB_ * NB_ * 4);

  auto T = [&](const float* src, int rs) {
    transpose_k<<<dim3(32, 32), 256, 0, stream>>>(src, wT, 1024, rs);
  };

  for (int b = 0; b < B_; ++b) {
    const float* tgt_b = targets + (size_t)b * SLC;
    const float* enc_b = encoded + (size_t)b * LE_ * D_;
    float* out_b = out + (size_t)b * SLC;

    ln_k<<<2048, 256, 0, stream>>>(tgt_b, ln1s, ln1b, XLN);
    T(wq1, 1024);
    gemm_k<0, u16, 0><<<dim3(8, 16), 256, 0, stream>>>(XLN, wT, nullptr, nullptr, Qb, 2048, 1024, 1024, 0);
    T(wk1, 1024);
    gemm_k<0, u16, 0><<<dim3(8, 16), 256, 0, stream>>>(XLN, wT, nullptr, nullptr, Kb, 2048, 1024, 1024, 0);
    T(wv1, 1024);
    gemm_k<0, u16, 0><<<dim3(8, 16), 256, 0, stream>>>(XLN, wT, nullptr, nullptr, Vb, 2048, 1024, 1024, 0);
    krep_k<<<64, 256, 0, stream>>>(Kb, KREP);
    sinkhorn_k<<<16, 256, 0, stream>>>(KREP, wsort, Pm);
    sortmix_k<<<1024, 256, 0, stream>>>(Pm, Kb, Vb, KSb, VSb);
    attn_mfma_k<0><<<256, 256, 0, stream>>>(Qb, Kb, Vb, KSb, VSb, Ob);
    T(wo1, 1024);
    gemm_k<1, float, 0><<<dim3(8, 16), 256, 0, stream>>>(Ob, wT, nullptr, tgt_b, out_b, 2048, 1024, 1024, 0);
    ln_k<<<2048, 256, 0, stream>>>(out_b, ln2s, ln2b, XLN);
    conv_k<<<1024, 256, 0, stream>>>(enc_b, Eb);
    T(wq2, 1024);
    gemm_k<0, u16, 0><<<dim3(8, 16), 256, 0, stream>>>(XLN, wT, nullptr, nullptr, Qb, 2048, 1024, 1024, 0);
    T(wk2, 1024);
    gemm_k<0, u16, 0><<<dim3(8, 8), 256, 0, stream>>>(Eb, wT, nullptr, nullptr, Kb, 1024, 1024, 1024, 0);
    T(wv2, 1024);
    gemm_k<0, u16, 0><<<dim3(8, 8), 256, 0, stream>>>(Eb, wT, nullptr, nullptr, Vb, 1024, 1024, 1024, 0);
    attn_mfma_k<1><<<256, 256, 0, stream>>>(Qb, Kb, Vb, nullptr, nullptr, Ob);
    T(wo2, 1024);
    gemm_k<1, float, 0><<<dim3(8, 16), 256, 0, stream>>>(Ob, wT, nullptr, out_b, out_b, 2048, 1024, 1024, 0);
    ln_k<<<2048, 256, 0, stream>>>(out_b, ln3s, ln3b, XLN);
    for (int c = 0; c < 4; ++c) {
      T(w1 + (size_t)c * 1024, 4096);
      gemm_k<2, u16, 0><<<dim3(8, 16), 256, 0, stream>>>(XLN, wT, b1 + c * 1024, nullptr, Hc,
                                                         2048, 1024, 1024, 0);
      T(w2 + (size_t)c * 1024 * 1024, 1024);
      if (c < 3)
        gemm_k<1, float, 0><<<dim3(8, 16), 256, 0, stream>>>(Hc, wT, nullptr, out_b, out_b,
                                                             2048, 1024, 1024, 0);
      else
        gemm_k<3, float, 0><<<dim3(8, 16), 256, 0, stream>>>(Hc, wT, b2, out_b, out_b,
                                                             2048, 1024, 1024, 0);
    }
  }
}

// Round 14
// 748.942 us; speedup vs baseline: 1.0269x; 1.0173x over previous
//
#include <hip/hip_runtime.h>

typedef unsigned short u16;
typedef unsigned int u32;
typedef __attribute__((ext_vector_type(8))) short short8;
typedef __attribute__((ext_vector_type(4))) short short4_t;
typedef __attribute__((ext_vector_type(4))) float float4_t;

#define B_ 4
#define LT_ 2048
#define LE_ 1024
#define D_ 1024
#define H_ 16
#define HD_ 64
#define NB_ 16
#define BS_ 128
#define M_ 4096
#define SCALE_ 0.125f

typedef __attribute__((address_space(1))) const void gas_t;
typedef __attribute__((address_space(3))) void las_t;

__device__ __forceinline__ float b2f(u16 u) {
  union { unsigned int i; float f; } v; v.i = ((unsigned int)u) << 16; return v.f;
}
__device__ __forceinline__ u16 f2b(float f) {
  union { float f; unsigned int i; } v; v.f = f;
  unsigned int x = v.i;
  return (u16)((x + 0x7fffu + ((x >> 16) & 1u)) >> 16);
}
__device__ __forceinline__ float gelu_f(float u) {
  // tanh-gelu via __expf: tanh(t) = 1 - 2/(exp(2t)+1)
  float t = 0.7978845608028654f * (u + 0.044715f * u * u * u);
  float th = 1.f - 2.f / (__expf(2.f * t) + 1.f);
  return 0.5f * u * (1.f + th);
}
__device__ __forceinline__ void store_val(u16* p, float x) { *p = f2b(x); }
__device__ __forceinline__ void store_val(float* p, float x) { *p = x; }

// ---------------- fp32 -> bf16 convert ----------------
__global__ __launch_bounds__(256)
void conv_k(const float* __restrict__ in, u16* __restrict__ out) {
  int i = (blockIdx.x * 256 + threadIdx.x) * 4;
  float4_t v = *(const float4_t*)(in + i);
  short4_t o;
  o[0] = (short)f2b(v[0]); o[1] = (short)f2b(v[1]);
  o[2] = (short)f2b(v[2]); o[3] = (short)f2b(v[3]);
  *(short4_t*)(out + i) = o;
}

// ---------------- transpose fp32 [R,Csub] (row stride) -> bf16 [Csub,R] ----------------
// (kept for the per-batch fallback path)
__global__ __launch_bounds__(256)
void transpose_k(const float* __restrict__ in, u16* __restrict__ out, int R, int rstride) {
  __shared__ u16 tile[32][33];
  int bx = blockIdx.x * 32, by = blockIdx.y * 32;
  int tx = threadIdx.x & 31, ty = threadIdx.x >> 5;
  #pragma unroll
  for (int y = ty; y < 32; y += 8)
    tile[y][tx] = f2b(in[(size_t)(by + y) * rstride + bx + tx]);
  __syncthreads();
  #pragma unroll
  for (int y = ty; y < 32; y += 8)
    out[(size_t)(bx + y) * R + by + tx] = tile[tx][y];
}

// ---------------- fused multi-transpose (one launch for all weight transposes) ----------
#define NJOBS 10
struct TJobs {
  const float* src[NJOBS];
  u16* dst[NJOBS];
  int outR[NJOBS];    // out row stride
  int inS[NJOBS];     // in row stride
  int ntx[NJOBS];     // tiles along out-row direction
  int ntiles[NJOBS];  // total tiles for this job
};

__global__ __launch_bounds__(256)
void prep_k(TJobs J) {
  int t = blockIdx.x, j = 0;
  while (t >= J.ntiles[j]) { t -= J.ntiles[j]; ++j; }   // uniform per block, <=10 iters
  const float* in = J.src[j];
  u16* out = J.dst[j];
  const int R = J.outR[j], rstride = J.inS[j];
  const int bx = (t % J.ntx[j]) * 32, by = (t / J.ntx[j]) * 32;
  __shared__ u16 tile[32][33];
  int tx = threadIdx.x & 31, ty = threadIdx.x >> 5;
  #pragma unroll
  for (int y = ty; y < 32; y += 8)
    tile[y][tx] = f2b(in[(size_t)(by + y) * rstride + bx + tx]);
  __syncthreads();
  #pragma unroll
  for (int y = ty; y < 32; y += 8)
    out[(size_t)(bx + y) * R + by + tx] = tile[tx][y];
}

// ---------------- layernorm (rows of 1024): fp32 in -> bf16 out ----------------
__global__ __launch_bounds__(256)
void ln_k(const float* __restrict__ x, const float* __restrict__ sw,
          const float* __restrict__ bw, u16* __restrict__ out) {
  int row = blockIdx.x, tid = threadIdx.x;
  const float* xr = x + (size_t)row * 1024 + tid * 4;
  float4_t raw = *(const float4_t*)xr;
  float v0 = raw[0], v1 = raw[1], v2 = raw[2], v3 = raw[3];
  float sum = v0 + v1 + v2 + v3;
  #pragma unroll
  for (int off = 32; off > 0; off >>= 1) sum += __shfl_down(sum, off, 64);
  __shared__ float sA[4], sB[4];
  int w = tid >> 6;
  if ((tid & 63) == 0) sA[w] = sum;
  __syncthreads();
  float mu = (sA[0] + sA[1] + sA[2] + sA[3]) * (1.f / 1024.f);
  float d0 = v0 - mu, d1 = v1 - mu, d2 = v2 - mu, d3 = v3 - mu;
  float s2 = d0 * d0 + d1 * d1 + d2 * d2 + d3 * d3;
  #pragma unroll
  for (int off = 32; off > 0; off >>= 1) s2 += __shfl_down(s2, off, 64);
  if ((tid & 63) == 0) sB[w] = s2;
  __syncthreads();
  float inv = rsqrtf((sB[0] + sB[1] + sB[2] + sB[3]) * (1.f / 1024.f) + 1e-6f);
  float4_t sv = *(const float4_t*)(sw + tid * 4);
  float4_t bv = *(const float4_t*)(bw + tid * 4);
  short4_t ov;
  ov[0] = (short)f2b(d0 * inv * sv[0] + bv[0]);
  ov[1] = (short)f2b(d1 * inv * sv[1] + bv[1]);
  ov[2] = (short)f2b(d2 * inv * sv[2] + bv[2]);
  ov[3] = (short)f2b(d3 * inv * sv[3] + bv[3]);
  *(short4_t*)(out + (size_t)row * 1024 + tid * 4) = ov;
}

// ---------------- MFMA GEMM (m97 structure, 2-barrier): fallback path only ------------
template<int EPI, typename TC, int SPLIT>
__global__ __launch_bounds__(256)
void gemm_k(const u16* __restrict__ A, const u16* __restrict__ Bt,
            const float* __restrict__ bias, const float* __restrict__ res,
            TC* __restrict__ C, int M, int N, int K, size_t cstride) {
  __shared__ __align__(16) u16 lA[128 * 32];
  __shared__ __align__(16) u16 lB[128 * 32];
  const int gx = gridDim.x;
  int lin = blockIdx.y * gx + blockIdx.x;
  const int nwg = gx * gridDim.y;
  if (!(nwg & 7)) {                    // all our grids are %8==0
    const int chunk = nwg >> 3;
    lin = (lin & 7) * chunk + (lin >> 3);
  }
  const int bn = (lin % gx) * 128;
  const int bm = (lin / gx) * 128;
  const int tid = threadIdx.x;
  const int lane = tid & 63;
  const int wave = tid >> 6;
  const int wy = wave >> 1, wx = wave & 1;
  const int quad = lane >> 4, l16 = lane & 15;

  float4_t acc[4][4];
  float4_t zz = {0.f, 0.f, 0.f, 0.f};
  #pragma unroll
  for (int i = 0; i < 4; ++i)
    #pragma unroll
    for (int j = 0; j < 4; ++j) acc[i][j] = zz;

  const int r0 = tid >> 2, kc0 = (tid & 3) * 8;       // u=0 chunk
  const u16* gA0 = A + (size_t)(bm + r0) * K + kc0;
  const u16* gA1 = A + (size_t)(bm + 64 + r0) * K + kc0;
  const u16* gB0 = Bt + (size_t)(bn + r0) * K + kc0;
  const u16* gB1 = Bt + (size_t)(bn + 64 + r0) * K + kc0;
  u16* lA0 = &lA[tid * 8];
  u16* lA1 = &lA[(tid + 256) * 8];
  u16* lB0 = &lB[tid * 8];
  u16* lB1 = &lB[(tid + 256) * 8];

  for (int k0 = 0; k0 < K; k0 += 32) {
    __syncthreads();
    __builtin_amdgcn_global_load_lds((gas_t*)(gA0 + k0), (las_t*)lA0, 16, 0, 0);
    __builtin_amdgcn_global_load_lds((gas_t*)(gA1 + k0), (las_t*)lA1, 16, 0, 0);
    __builtin_amdgcn_global_load_lds((gas_t*)(gB0 + k0), (las_t*)lB0, 16, 0, 0);
    __builtin_amdgcn_global_load_lds((gas_t*)(gB1 + k0), (las_t*)lB1, 16, 0, 0);
    __syncthreads();
    short8 af[4], bfr[4];
    #pragma unroll
    for (int i = 0; i < 4; ++i)
      af[i] = *(const short8*)&lA[(wy * 64 + i * 16 + l16) * 32 + quad * 8];
    #pragma unroll
    for (int j = 0; j < 4; ++j)
      bfr[j] = *(const short8*)&lB[(wx * 64 + j * 16 + l16) * 32 + quad * 8];
    #pragma unroll
    for (int i = 0; i < 4; ++i)
      #pragma unroll
      for (int j = 0; j < 4; ++j)
        acc[i][j] = __builtin_amdgcn_mfma_f32_16x16x32_bf16(af[i], bfr[j], acc[i][j], 0, 0, 0);
  }

  #pragma unroll
  for (int i = 0; i < 4; ++i) {
    int row = bm + wy * 64 + i * 16 + quad * 4;
    #pragma unroll
    for (int j = 0; j < 4; ++j) {
      int col = bn + wx * 64 + j * 16 + l16;
      TC* Cb = SPLIT ? (C + (size_t)(col >> 10) * cstride) : C;
      int ccol = SPLIT ? (col & 1023) : col;
      int cn = SPLIT ? 1024 : N;
      #pragma unroll
      for (int v = 0; v < 4; ++v) {
        float x = acc[i][j][v];
        size_t idx = (size_t)(row + v) * cn + ccol;
        if (EPI == 1) {
          x += res[idx];
        } else if (EPI == 2) {
          x = gelu_f(x + bias[col]);
        } else if (EPI == 3) {
          x += bias[col] + res[idx];
        }
        store_val(&Cb[idx], x);
      }
    }
  }
}

// ---------------- 128x128 deep-pipelined GEMM (counted-vmcnt, 2 blocks/CU) ----------
// Round-13: conflicts 0 (row-bits-1-2 swizzle verified), ~551 TF/site. Used for
// all sites whose grids would quantize badly on the 256^2 kernel (1-round-exact
// at 2/CU or 3-round-exact for QKV).
template<int EPI, typename TC, int SPLIT>
__global__ __launch_bounds__(256, 2)
void gemm128d_k(const u16* __restrict__ A, const u16* __restrict__ Bt,
                const float* __restrict__ bias, const float* __restrict__ res,
                TC* __restrict__ C, int M, int N, int K, size_t cstride) {
  __shared__ __align__(16) u16 lA[4][128 * 32];
  __shared__ __align__(16) u16 lB[4][128 * 32];
  const int gx = gridDim.x;
  int lin = blockIdx.y * gx + blockIdx.x;
  const int nwg = gx * gridDim.y;
  if (!(nwg & 7)) {
    const int chunk = nwg >> 3;
    lin = (lin & 7) * chunk + (lin >> 3);
  }
  const int bn = (lin % gx) * 128;
  const int bm = (lin / gx) * 128;
  const int tid = threadIdx.x;
  const int lane = tid & 63;
  const int wave = tid >> 6;
  const int wy = wave >> 1, wx = wave & 1;
  const int quad = lane >> 4, l16 = lane & 15;
  const int slo = (quad ^ ((l16 >> 1) & 3)) * 8;  // swizzled slot (row bits 1-2)

  float4_t acc[4][4];
  float4_t zz = {0.f, 0.f, 0.f, 0.f};
  #pragma unroll
  for (int i = 0; i < 4; ++i)
    #pragma unroll
    for (int j = 0; j < 4; ++j) acc[i][j] = zz;

  const int r0 = tid >> 2;
  const int kc0 = ((tid & 3) ^ ((r0 >> 1) & 3)) * 8;  // pre-swizzled global k-col
  const u16* gA0 = A + (size_t)(bm + r0) * K + kc0;
  const u16* gA1 = A + (size_t)(bm + 64 + r0) * K + kc0;
  const u16* gB0 = Bt + (size_t)(bn + r0) * K + kc0;
  const u16* gB1 = Bt + (size_t)(bn + 64 + r0) * K + kc0;
  const int NT = K >> 5;

  #define STAGE128(TT, BUF)                                                      \
    {                                                                            \
      int kk_ = (TT) * 32;                                                       \
      __builtin_amdgcn_global_load_lds((gas_t*)(gA0 + kk_),                      \
          (las_t*)&lA[BUF][tid * 8], 16, 0, 0);                                  \
      __builtin_amdgcn_global_load_lds((gas_t*)(gA1 + kk_),                      \
          (las_t*)&lA[BUF][(tid + 256) * 8], 16, 0, 0);                          \
      __builtin_amdgcn_global_load_lds((gas_t*)(gB0 + kk_),                      \
          (las_t*)&lB[BUF][tid * 8], 16, 0, 0);                                  \
      __builtin_amdgcn_global_load_lds((gas_t*)(gB1 + kk_),                      \
          (las_t*)&lB[BUF][(tid + 256) * 8], 16, 0, 0);                          \
    }

  STAGE128(0, 0)
  STAGE128(1, 1)
  STAGE128(2, 2)

  for (int t = 0; t < NT; ++t) {
    asm volatile("s_waitcnt vmcnt(8)" ::: "memory");   // tile t resident; t+1,t+2 in flight
    __builtin_amdgcn_s_barrier();
    __builtin_amdgcn_sched_barrier(0);
    int ts = t + 3; if (ts > NT - 1) ts = NT - 1;      // tail: dummy re-stage, dead buffer
    STAGE128(ts, (t + 3) & 3)
    const u16* bufA = &lA[t & 3][0];
    const u16* bufB = &lB[t & 3][0];
    short8 af[4], bfr[4];
    #pragma unroll
    for (int i = 0; i < 4; ++i)
      af[i] = *(const short8*)&bufA[(wy * 64 + i * 16 + l16) * 32 + slo];
    #pragma unroll
    for (int j = 0; j < 4; ++j)
      bfr[j] = *(const short8*)&bufB[(wx * 64 + j * 16 + l16) * 32 + slo];
    __builtin_amdgcn_s_setprio(1);
    #pragma unroll
    for (int i = 0; i < 4; ++i)
      #pragma unroll
      for (int j = 0; j < 4; ++j)
        acc[i][j] = __builtin_amdgcn_mfma_f32_16x16x32_bf16(af[i], bfr[j], acc[i][j], 0, 0, 0);
    __builtin_amdgcn_s_setprio(0);
  }
  #undef STAGE128

  #pragma unroll
  for (int i = 0; i < 4; ++i) {
    int row = bm + wy * 64 + i * 16 + quad * 4;
    #pragma unroll
    for (int j = 0; j < 4; ++j) {
      int col = bn + wx * 64 + j * 16 + l16;
      TC* Cb = SPLIT ? (C + (size_t)(col >> 10) * cstride) : C;
      int ccol = SPLIT ? (col & 1023) : col;
      int cn = SPLIT ? 1024 : N;
      #pragma unroll
      for (int v = 0; v < 4; ++v) {
        float x = acc[i][j][v];
        size_t idx = (size_t)(row + v) * cn + ccol;
        if (EPI == 1) {
          x += res[idx];
        } else if (EPI == 2) {
          x = gelu_f(x + bias[col]);
        } else if (EPI == 3) {
          x += bias[col] + res[idx];
        }
        store_val(&Cb[idx], x);
      }
    }
  }
}

// ---------------- 256x256 deep-pipelined MFMA GEMM (counted-vmcnt) -----------------
// Measured best at MLP1 (512 blocks = 2 exact rounds at 1/CU): 112us (round 10)
// vs 124.6us on gemm128d even with conflicts 0 (round 13).
template<int EPI, typename TC, int SPLIT>
__global__ __launch_bounds__(512, 2)
void gemm256_k(const u16* __restrict__ A, const u16* __restrict__ Bt,
               const float* __restrict__ bias, const float* __restrict__ res,
               TC* __restrict__ C, int M, int N, int K, size_t cstride) {
  __shared__ __align__(16) u16 lA[4][256 * 32];
  __shared__ __align__(16) u16 lB[4][256 * 32];
  const int gx = gridDim.x;
  int lin = blockIdx.y * gx + blockIdx.x;
  const int nwg = gx * gridDim.y;
  if (!(nwg & 7)) {
    const int chunk = nwg >> 3;
    lin = (lin & 7) * chunk + (lin >> 3);
  }
  const int bn = (lin % gx) * 256;
  const int bm = (lin / gx) * 256;
  const int tid = threadIdx.x;
  const int lane = tid & 63;
  const int wave = tid >> 6;
  const int wy = wave >> 2, wx = wave & 3;        // 2 x 4 waves
  const int quad = lane >> 4, l16 = lane & 15;
  const int slo = ((quad ^ ((l16 >> 1) & 3)) << 4);  // swizzled 16B slot (bytes)

  int lrow[2], kcs[2];
  #pragma unroll
  for (int u = 0; u < 2; ++u) {
    int p = (tid + u * 512) * 16;
    int lg = p ^ (((p >> 7) & 3) << 4);
    lrow[u] = lg >> 6;
    kcs[u] = (lg & 63) >> 1;
  }
  const u16* gA[2]; const u16* gB[2];
  #pragma unroll
  for (int u = 0; u < 2; ++u) {
    gA[u] = A + (size_t)(bm + lrow[u]) * K + kcs[u];
    gB[u] = Bt + (size_t)(bn + lrow[u]) * K + kcs[u];
  }
  const int NT = K >> 5;

  float4_t acc[8][4];
  float4_t zz = {0.f, 0.f, 0.f, 0.f};
  #pragma unroll
  for (int i = 0; i < 8; ++i)
    #pragma unroll
    for (int j = 0; j < 4; ++j) acc[i][j] = zz;

  #define STAGE256(TT, BUF)                                                      \
    {                                                                            \
      int kk_ = (TT) * 32;                                                       \
      __builtin_amdgcn_global_load_lds((gas_t*)(gA[0] + kk_),                    \
          (las_t*)((char*)&lA[BUF][0] + tid * 16), 16, 0, 0);                    \
      __builtin_amdgcn_global_load_lds((gas_t*)(gA[1] + kk_),                    \
          (las_t*)((char*)&lA[BUF][0] + (tid + 512) * 16), 16, 0, 0);            \
      __builtin_amdgcn_global_load_lds((gas_t*)(gB[0] + kk_),                    \
          (las_t*)((char*)&lB[BUF][0] + tid * 16), 16, 0, 0);                    \
      __builtin_amdgcn_global_load_lds((gas_t*)(gB[1] + kk_),                    \
          (las_t*)((char*)&lB[BUF][0] + (tid + 512) * 16), 16, 0, 0);            \
    }

  STAGE256(0, 0)
  STAGE256(1, 1)
  STAGE256(2, 2)

  for (int t = 0; t < NT; ++t) {
    asm volatile("s_waitcnt vmcnt(8)" ::: "memory");   // tile t resident; t+1,t+2 in flight
    __builtin_amdgcn_s_barrier();
    __builtin_amdgcn_sched_barrier(0);
    int ts = t + 3; if (ts > NT - 1) ts = NT - 1;      // tail: dummy re-stage, dead buffer
    STAGE256(ts, (t + 3) & 3)
    const char* bufA = (const char*)&lA[t & 3][0];
    const char* bufB = (const char*)&lB[t & 3][0];
    short8 af[8], bf[4];
    #pragma unroll
    for (int i = 0; i < 8; ++i)
      af[i] = *(const short8*)(bufA + (wy * 128 + i * 16 + l16) * 64 + slo);
    #pragma unroll
    for (int j = 0; j < 4; ++j)
      bf[j] = *(const short8*)(bufB + (wx * 64 + j * 16 + l16) * 64 + slo);
    __builtin_amdgcn_s_setprio(1);
    #pragma unroll
    for (int i = 0; i < 8; ++i)
      #pragma unroll
      for (int j = 0; j < 4; ++j)
        acc[i][j] = __builtin_amdgcn_mfma_f32_16x16x32_bf16(af[i], bf[j], acc[i][j], 0, 0, 0);
    __builtin_amdgcn_s_setprio(0);
  }
  #undef STAGE256

  #pragma unroll
  for (int i = 0; i < 8; ++i) {
    int row = bm + wy * 128 + i * 16 + quad * 4;
    #pragma unroll
    for (int j = 0; j < 4; ++j) {
      int col = bn + wx * 64 + j * 16 + l16;
      TC* Cb = SPLIT ? (C + (size_t)(col >> 10) * cstride) : C;
      int ccol = SPLIT ? (col & 1023) : col;
      int cn = SPLIT ? 1024 : N;
      #pragma unroll
      for (int v = 0; v < 4; ++v) {
        float x = acc[i][j][v];
        size_t idx = (size_t)(row + v) * cn + ccol;
        if (EPI == 1) {
          x += res[idx];
        } else if (EPI == 2) {
          x = gelu_f(x + bias[col]);
        } else if (EPI == 3) {
          x += bias[col] + res[idx];
        }
        store_val(&Cb[idx], x);
      }
    }
  }
}

// ---------------- krep: sum k over block rows (b decoded from idx) ----------------
__global__ __launch_bounds__(256)
void krep_k(const u16* __restrict__ K1, float* __restrict__ krep) {
  int idx = blockIdx.x * 256 + threadIdx.x;   // (#batches)*NB*1024
  int col = idx & 1023;
  int bn = idx >> 10;
  const u16* p = K1 + (size_t)bn * 128 * 1024 + col;
  float s = 0.f;
  for (int i = 0; i < 128; ++i) s += b2f(p[(size_t)i * 1024]);
  krep[idx] = s;
}

// ---------------- sinkhorn: grid = (#batches)*H, one (b,h) each ----------------
__global__ __launch_bounds__(256)
void sinkhorn_k(const float* __restrict__ krep, const float* __restrict__ wsort,
                float* __restrict__ P) {
  int bh = blockIdx.x;
  int b = bh >> 4, h = bh & 15;
  int t = threadIdx.x;
  int i = t >> 4, j = t & 15;
  __shared__ float la[16][17];
  __shared__ float red[16];
  float acc = 0.f;
  const float* kr = krep + ((size_t)b * 16 + i) * 1024 + h * 64;
  const float* ws = wsort + (size_t)h * 64 * 16 + j;
  for (int k = 0; k < 64; ++k) acc += kr[k] * ws[k * 16];
  la[i][j] = (j <= i) ? acc : -1e9f;
  __syncthreads();
  for (int it = 0; it < 5; ++it) {
    if (t < 16) {
      float m = -1e30f;
      for (int jj = 0; jj < 16; ++jj) m = fmaxf(m, la[t][jj]);
      float s = 0.f;
      for (int jj = 0; jj < 16; ++jj) s += __expf(la[t][jj] - m);
      red[t] = m + __logf(s);
    }
    __syncthreads();
    la[i][j] = (j <= i) ? la[i][j] - red[i] : -1e9f;
    __syncthreads();
    if (t < 16) {
      float m = -1e30f;
      for (int ii = 0; ii < 16; ++ii) m = fmaxf(m, la[ii][t]);
      float s = 0.f;
      for (int ii = 0; ii < 16; ++ii) s += __expf(la[ii][t] - m);
      red[t] = m + __logf(s);
    }
    __syncthreads();
    la[i][j] = (j <= i) ? la[i][j] - red[j] : -1e9f;
    __syncthreads();
  }
  P[((size_t)bh * 16 + i) * 16 + j] = __expf(la[i][j]);
}

// ---------------- sorted block mix (b decoded from idx), short8 loads ----------------
__global__ __launch_bounds__(256)
void sortmix_k(const float* __restrict__ P, const u16* __restrict__ K1,
               const u16* __restrict__ V1, u16* __restrict__ KS,
               u16* __restrict__ VS) {
  int t = blockIdx.x * 256 + threadIdx.x;     // (#batches)*2048*128 (8 cols each)
  int col = (t & 127) * 8;
  int rest = t >> 7;                          // b*2048 + i*128 + s
  int b = rest >> 11, is = rest & 2047, i = is >> 7, s = is & 127;
  int h = col >> 6;                           // 8-col chunk never straddles a head
  const float* Pr = P + (((size_t)(b * 16 + h)) * 16 + i) * 16;
  size_t base = ((size_t)(b * 2048 + s)) * 1024 + col;
  float ka[8] = {0, 0, 0, 0, 0, 0, 0, 0}, va[8] = {0, 0, 0, 0, 0, 0, 0, 0};
  for (int j = 0; j <= i; ++j) {   // P[i][j]==0 for j>i (causal mask)
    float p = Pr[j];
    short8 kk = *(const short8*)&K1[base + (size_t)j * 131072];
    short8 vv = *(const short8*)&V1[base + (size_t)j * 131072];
    #pragma unroll
    for (int e = 0; e < 8; ++e) {
      ka[e] += p * b2f((u16)kk[e]);
      va[e] += p * b2f((u16)vv[e]);
    }
  }
  size_t ob = ((size_t)(b * 2048 + i * 128 + s)) * 1024 + col;
  short8 ok, ov;
  #pragma unroll
  for (int e = 0; e < 8; ++e) { ok[e] = (short)f2b(ka[e]); ov[e] = (short)f2b(va[e]); }
  *(short8*)&KS[ob] = ok;
  *(short8*)&VS[ob] = ov;
}

// ---------------- MFMA flash attention (conflict-free LDS redesign) ----------------
// Verified correct on HW rounds 8-13. kls XOR-swizzled, V transposed via 2-pass
// LDS (b128 writes), P in registers via shfl-assembled PV A-fragments.
template<int CROSS>
__global__ __launch_bounds__(256)
void attn_mfma_k(const u16* __restrict__ Q, const u16* __restrict__ Ka,
                 const u16* __restrict__ Va, const u16* __restrict__ Kb2,
                 const u16* __restrict__ Vb2, u16* __restrict__ O) {
  __shared__ __align__(16) u16 kls[128 * 64];
  __shared__ __align__(16) u16 vlin[128 * 64];
  __shared__ __align__(16) u16 vtls[64 * 128];
  int blk = blockIdx.x;
  {
    int nwg = gridDim.x;
    if (!(nwg & 7)) { int ch = nwg >> 3; blk = (blk & 7) * ch + (blk >> 3); }
  }
  const int n = blk & 15, h = (blk >> 4) & 15, b = blk >> 8;
  const int tid = threadIdx.x, lane = tid & 63, wv = tid >> 6;
  const int quad = lane >> 4, l16 = lane & 15;
  const int m0 = wv * 32;
  const size_t qrowbase = (size_t)b * 2048 + n * 128;

  short8 qa[2][2];
  #pragma unroll
  for (int qi = 0; qi < 2; ++qi)
    #pragma unroll
    for (int ks = 0; ks < 2; ++ks)
      qa[qi][ks] = *(const short8*)&Q[(qrowbase + m0 + qi * 16 + l16) * 1024 +
                                      h * 64 + ks * 32 + quad * 8];

  float4_t acc_o[2][4];
  float mrow[2], lrow[2];
  #pragma unroll
  for (int mi = 0; mi < 2; ++mi) {
    #pragma unroll
    for (int dn = 0; dn < 4; ++dn) acc_o[mi][dn] = {0.f, 0.f, 0.f, 0.f};
    mrow[mi] = -1e30f; lrow[mi] = 0.f;
  }

  const int NT = CROSS ? 8 : 2;
  for (int t = 0; t < NT; ++t) {
    const u16 *Kg, *Vg;
    bool causal = false;
    if (CROSS) {
      size_t kb = ((size_t)b * 1024 + t * 128) * 1024 + h * 64;
      Kg = Ka + kb; Vg = Va + kb;
    } else if (t == 0) {
      size_t kb = qrowbase * 1024 + h * 64;
      Kg = Ka + kb; Vg = Va + kb; causal = true;
    } else {
      size_t kb = qrowbase * 1024 + h * 64;
      Kg = Kb2 + kb; Vg = Vb2 + kb;
    }
    // ---- stage K (swizzled) + V (linear) ----
    #pragma unroll
    for (int i = 0; i < 4; ++i) {
      int c = tid + i * 256;
      int row = c >> 3, slot = c & 7, dd = slot * 8;
      short8 kv8 = *(const short8*)&Kg[(size_t)row * 1024 + dd];
      *(short8*)&kls[row * 64 + ((slot ^ (row & 7)) * 8)] = kv8;
      short8 vv8 = *(const short8*)&Vg[(size_t)row * 1024 + dd];
      *(short8*)&vlin[row * 64 + dd] = vv8;
    }
    __syncthreads();                       // bar1: staging visible

    // ---- transpose vlin -> vtls (conflict-free) ----
    #pragma unroll
    for (int ii = 0; ii < 4; ++ii) {
      int d = tid & 63;
      int kvg = (tid >> 6) * 4 + ii;       // 0..15
      union { short8 s8; u16 us[8]; } tt;
      #pragma unroll
      for (int j = 0; j < 8; ++j)
        tt.us[j] = vlin[(kvg * 8 + j) * 64 + d];
      int slotp = (kvg & 8) | ((kvg ^ (d & 7)) & 7);
      *(short8*)&vtls[d * 128 + slotp * 8] = tt.s8;
    }

    // ---- QK^T, swapped operands: s[qi][nj] holds S^T (kv on quad*4+v, q on l16)
    float4_t s[2][8];
    #pragma unroll
    for (int qi = 0; qi < 2; ++qi)
      #pragma unroll
      for (int nj = 0; nj < 8; ++nj) s[qi][nj] = {0.f, 0.f, 0.f, 0.f};
    #pragma unroll
    for (int nj = 0; nj < 8; ++nj) {
      int r = nj * 16 + l16;
      short8 k0 = *(const short8*)&kls[r * 64 + ((quad ^ (l16 & 7)) * 8)];
      short8 k1 = *(const short8*)&kls[r * 64 + (((4 + quad) ^ (l16 & 7)) * 8)];
      #pragma unroll
      for (int qi = 0; qi < 2; ++qi) {
        s[qi][nj] = __builtin_amdgcn_mfma_f32_16x16x32_bf16(k0, qa[qi][0], s[qi][nj], 0, 0, 0);
        s[qi][nj] = __builtin_amdgcn_mfma_f32_16x16x32_bf16(k1, qa[qi][1], s[qi][nj], 0, 0, 0);
      }
    }

    // ---- lane-local online softmax; P kept in registers as bf16 pairs
    float crv[2];
    u32 p01[2][8], p23[2][8];
    #pragma unroll
    for (int qi = 0; qi < 2; ++qi) {
      const int qrow = m0 + qi * 16 + l16;     // block-local q row
      float mx = -1e30f;
      #pragma unroll
      for (int nj = 0; nj < 8; ++nj)
        #pragma unroll
        for (int v = 0; v < 4; ++v) {
          float x = s[qi][nj][v] * SCALE_;
          if (causal && (nj * 16 + quad * 4 + v > qrow)) x = -1e30f;
          s[qi][nj][v] = x;
          mx = fmaxf(mx, x);
        }
      mx = fmaxf(mx, __shfl_xor(mx, 16, 64));
      mx = fmaxf(mx, __shfl_xor(mx, 32, 64));
      float mn = fmaxf(mrow[qi], mx);
      crv[qi] = __expf(mrow[qi] - mn);
      mrow[qi] = mn;
      float rs = 0.f;
      #pragma unroll
      for (int nj = 0; nj < 8; ++nj)
        #pragma unroll
        for (int v = 0; v < 4; ++v) {
          float p = __expf(s[qi][nj][v] - mn);
          s[qi][nj][v] = p;
          rs += p;
        }
      rs += __shfl_xor(rs, 16, 64);
      rs += __shfl_xor(rs, 32, 64);
      lrow[qi] = lrow[qi] * crv[qi] + rs;
      #pragma unroll
      for (int nj = 0; nj < 8; ++nj) {
        p01[qi][nj] = (u32)f2b(s[qi][nj][0]) | ((u32)f2b(s[qi][nj][1]) << 16);
        p23[qi][nj] = (u32)f2b(s[qi][nj][2]) | ((u32)f2b(s[qi][nj][3]) << 16);
      }
    }
    // rescale accumulator: acc_o rows are q = m0 + mi*16 + quad*4 + v,
    // whose cr lives in lane l16 = quad*4+v (any quad; pick same quad).
    #pragma unroll
    for (int mi = 0; mi < 2; ++mi)
      #pragma unroll
      for (int v = 0; v < 4; ++v) {
        float c = __shfl(crv[mi], quad * 20 + v, 64);
        #pragma unroll
        for (int dn = 0; dn < 4; ++dn) acc_o[mi][dn][v] *= c;
      }

    __syncthreads();                       // bar2: vtls transpose visible

    // ---- PV: A-frag assembled in-register via shfl; B-frag from swizzled vtls
    const int src0 = (quad & 1) * 32 + l16;   // qs0*16 + l16
    const int src1 = src0 + 16;
    const bool hi = (quad >> 1) != 0;
    #pragma unroll
    for (int ks = 0; ks < 4; ++ks) {
      union { short8 s8; u32 u[4]; } au[2];
      #pragma unroll
      for (int qi = 0; qi < 2; ++qi) {
        u32 w0a = __shfl(p01[qi][2 * ks],     src0, 64);
        u32 w0b = __shfl(p01[qi][2 * ks + 1], src0, 64);
        u32 w1a = __shfl(p23[qi][2 * ks],     src0, 64);
        u32 w1b = __shfl(p23[qi][2 * ks + 1], src0, 64);
        u32 w2a = __shfl(p01[qi][2 * ks],     src1, 64);
        u32 w2b = __shfl(p01[qi][2 * ks + 1], src1, 64);
        u32 w3a = __shfl(p23[qi][2 * ks],     src1, 64);
        u32 w3b = __shfl(p23[qi][2 * ks + 1], src1, 64);
        au[qi].u[0] = hi ? w0b : w0a;
        au[qi].u[1] = hi ? w1b : w1a;
        au[qi].u[2] = hi ? w2b : w2a;
        au[qi].u[3] = hi ? w3b : w3a;
      }
      #pragma unroll
      for (int dn = 0; dn < 4; ++dn) {
        int dR = dn * 16 + l16;
        int sbase = ks * 4 + quad;
        int sp = (sbase & 8) | ((sbase ^ (l16 & 7)) & 7);
        short8 bv = *(const short8*)&vtls[dR * 128 + sp * 8];
        acc_o[0][dn] = __builtin_amdgcn_mfma_f32_16x16x32_bf16(au[0].s8, bv, acc_o[0][dn], 0, 0, 0);
        acc_o[1][dn] = __builtin_amdgcn_mfma_f32_16x16x32_bf16(au[1].s8, bv, acc_o[1][dn], 0, 0, 0);
      }
    }
  }
  #pragma unroll
  for (int mi = 0; mi < 2; ++mi) {
    float invl = 1.f / lrow[mi];
    #pragma unroll
    for (int v = 0; v < 4; ++v) {
      float inv = __shfl(invl, quad * 20 + v, 64);
      int rowl = m0 + mi * 16 + quad * 4 + v;
      #pragma unroll
      for (int dn = 0; dn < 4; ++dn)
        O[(qrowbase + rowl) * 1024 + h * 64 + dn * 16 + l16] =
            f2b(acc_o[mi][dn][v] * inv);
    }
  }
}

// ---------------- host ----------------
extern "C" void kernel_launch(void* const* d_in, const int* in_sizes, int n_in,
                              void* d_out, int out_size, void* d_ws, size_t ws_size,
                              hipStream_t stream) {
  const float* targets = (const float*)d_in[0];
  const float* encoded = (const float*)d_in[1];
  const float* ln1s = (const float*)d_in[2];
  const float* ln1b = (const float*)d_in[3];
  const float* ln2s = (const float*)d_in[4];
  const float* ln2b = (const float*)d_in[5];
  const float* ln3s = (const float*)d_in[6];
  const float* ln3b = (const float*)d_in[7];
  const float* wq1 = (const float*)d_in[8];
  const float* wk1 = (const float*)d_in[9];
  const float* wv1 = (const float*)d_in[10];
  const float* wo1 = (const float*)d_in[11];
  const float* wsort = (const float*)d_in[12];
  const float* wq2 = (const float*)d_in[13];
  const float* wk2 = (const float*)d_in[14];
  const float* wv2 = (const float*)d_in[15];
  const float* wo2 = (const float*)d_in[16];
  const float* w1 = (const float*)d_in[17];
  const float* b1 = (const float*)d_in[18];
  const float* w2 = (const float*)d_in[19];
  const float* b2 = (const float*)d_in[20];
  float* out = (float*)d_out;
  (void)in_sizes; (void)n_in; (void)out_size;

  char* ws = (char*)d_ws;
  size_t off = 0;
  auto alloc = [&](size_t n) -> char* {
    char* p = ws + off;
    off += (n + 255) & ~(size_t)255;
    return p;
  };

  const size_t NTD = (size_t)B_ * LT_ * D_;         // 8.4M elems
  const size_t NEED_BIG = (size_t)(8 * 2 + 8 + 8) * 1024 * 1024   // weights bf16
                        + (size_t)LE_ * B_ * D_ * 2                // Eb
                        + NTD * 2 * 7                              // XLN + 6 act
                        + (1u << 20);                              // small + slack

  if (ws_size >= NEED_BIG) {
    // ---------- whole-batch path ----------
    u16* wq1t = (u16*)alloc((size_t)1024 * 1024 * 2);
    u16* wk1t = (u16*)alloc((size_t)1024 * 1024 * 2);
    u16* wv1t = (u16*)alloc((size_t)1024 * 1024 * 2);
    u16* wo1t = (u16*)alloc((size_t)1024 * 1024 * 2);
    u16* wq2t = (u16*)alloc((size_t)1024 * 1024 * 2);
    u16* wk2t = (u16*)alloc((size_t)1024 * 1024 * 2);
    u16* wv2t = (u16*)alloc((size_t)1024 * 1024 * 2);
    u16* wo2t = (u16*)alloc((size_t)1024 * 1024 * 2);
    u16* w1t = (u16*)alloc((size_t)4096 * 1024 * 2);
    u16* w2t = (u16*)alloc((size_t)1024 * 4096 * 2);
    u16* Eb  = (u16*)alloc((size_t)B_ * LE_ * D_ * 2);
    u16* XLN = (u16*)alloc(NTD * 2);
    u16* Qb  = (u16*)alloc(NTD * 2);    // Qb..KSb (67.1MB contiguous) = MLP hidden
    u16* Kb  = (u16*)alloc(NTD * 2);
    u16* Vb  = (u16*)alloc(NTD * 2);
    u16* KSb = (u16*)alloc(NTD * 2);
    u16* VSb = (u16*)alloc(NTD * 2);
    u16* Ob  = (u16*)alloc(NTD * 2);
    float* KREP = (float*)alloc((size_t)B_ * NB_ * 1024 * 4);
    float* Pm = (float*)alloc((size_t)B_ * H_ * NB_ * NB_ * 4);
    u16* HML = Qb;

    // one fused launch for all 10 weight transposes
    TJobs J;
    const float* srcs[NJOBS] = {wq1, wk1, wv1, wo1, wq2, wk2, wv2, wo2, w1, w2};
    u16* dsts[NJOBS] = {wq1t, wk1t, wv1t, wo1t, wq2t, wk2t, wv2t, wo2t, w1t, w2t};
    int total = 0;
    for (int j = 0; j < NJOBS; ++j) {
      J.src[j] = srcs[j]; J.dst[j] = dsts[j];
      if (j < 8)      { J.outR[j] = 1024; J.inS[j] = 1024; J.ntx[j] = 32;  J.ntiles[j] = 1024; }
      else if (j == 8){ J.outR[j] = 1024; J.inS[j] = 4096; J.ntx[j] = 128; J.ntiles[j] = 4096; }
      else            { J.outR[j] = 4096; J.inS[j] = 1024; J.ntx[j] = 32;  J.ntiles[j] = 4096; }
      total += J.ntiles[j];
    }
    prep_k<<<total, 256, 0, stream>>>(J);
    conv_k<<<4096, 256, 0, stream>>>(encoded, Eb);

    ln_k<<<8192, 256, 0, stream>>>(targets, ln1s, ln1b, XLN);
    // fused QKV projection on 128^2 deep-pipelined kernel: 1536 blocks at
    // 2/CU = 3 exactly-full rounds
    gemm128d_k<0, u16, 1><<<dim3(24, 64), 256, 0, stream>>>(XLN, wq1t, nullptr, nullptr,
                                                            Qb, 8192, 3072, 1024, NTD);
    krep_k<<<256, 256, 0, stream>>>(Kb, KREP);
    sinkhorn_k<<<64, 256, 0, stream>>>(KREP, wsort, Pm);
    sortmix_k<<<4096, 256, 0, stream>>>(Pm, Kb, Vb, KSb, VSb);
    attn_mfma_k<0><<<1024, 256, 0, stream>>>(Qb, Kb, Vb, KSb, VSb, Ob);
    gemm128d_k<1, float, 0><<<dim3(8, 64), 256, 0, stream>>>(Ob, wo1t, nullptr, targets, out, 8192, 1024, 1024, 0);
    ln_k<<<8192, 256, 0, stream>>>(out, ln2s, ln2b, XLN);
    gemm128d_k<0, u16, 0><<<dim3(8, 64), 256, 0, stream>>>(XLN, wq2t, nullptr, nullptr, Qb, 8192, 1024, 1024, 0);
    // fused K2/V2 projection of encoded: Bt = [wk2t;wv2t] (N=2048), split -> Kb/Vb
    gemm128d_k<0, u16, 1><<<dim3(16, 32), 256, 0, stream>>>(Eb, wk2t, nullptr, nullptr, Kb, 4096, 2048, 1024, NTD);
    attn_mfma_k<1><<<1024, 256, 0, stream>>>(Qb, Kb, Vb, nullptr, nullptr, Ob);
    gemm128d_k<1, float, 0><<<dim3(8, 64), 256, 0, stream>>>(Ob, wo2t, nullptr, out, out, 8192, 1024, 1024, 0);
    ln_k<<<8192, 256, 0, stream>>>(out, ln3s, ln3b, XLN);
    // MLP1 on gemm256_k: 512 blocks = 2 exact rounds at 1/CU, measured 112us
    // (vs 124.6us on gemm128d even with 0 conflicts)
    gemm256_k<2, u16, 0><<<dim3(16, 32), 512, 0, stream>>>(XLN, w1t, b1, nullptr, HML, 8192, 4096, 1024, 0);
    gemm128d_k<3, float, 0><<<dim3(8, 64), 256, 0, stream>>>(HML, w2t, b2, out, out, 8192, 1024, 4096, 0);
    return;
  }

  // ---------- per-batch fallback (~36 MB) ----------
  const size_t SLC = (size_t)LT_ * D_;
  u16* wT  = (u16*)alloc((size_t)1024 * 1024 * 2);
  u16* XLN = (u16*)alloc(SLC * 2);
  u16* Qb  = (u16*)alloc(SLC * 2);
  u16* Kb  = (u16*)alloc(SLC * 2);
  u16* Vb  = (u16*)alloc(SLC * 2);
  u16* KSb = (u16*)alloc(SLC * 2);
  u16* VSb = (u16*)alloc(SLC * 2);
  u16* Ob  = (u16*)alloc(SLC * 2);
  u16* Hc  = (u16*)alloc(SLC * 2);
  u16* Eb  = (u16*)alloc((size_t)LE_ * D_ * 2);
  float* KREP = (float*)alloc((size_t)NB_ * 1024 * 4);
  float* Pm = (float*)alloc((size_t)H_ * NB_ * NB_ * 4);

  auto T = [&](const float* src, int rs) {
    transpose_k<<<dim3(32, 32), 256, 0, stream>>>(src, wT, 1024, rs);
  };

  for (int b = 0; b < B_; ++b) {
    const float* tgt_b = targets + (size_t)b * SLC;
    const float* enc_b = encoded + (size_t)b * LE_ * D_;
    float* out_b = out + (size_t)b * SLC;

    ln_k<<<2048, 256, 0, stream>>>(tgt_b, ln1s, ln1b, XLN);
    T(wq1, 1024);
    gemm_k<0, u16, 0><<<dim3(8, 16), 256, 0, stream>>>(XLN, wT, nullptr, nullptr, Qb, 2048, 1024, 1024, 0);
    T(wk1, 1024);
    gemm_k<0, u16, 0><<<dim3(8, 16), 256, 0, stream>>>(XLN, wT, nullptr, nullptr, Kb, 2048, 1024, 1024, 0);
    T(wv1, 1024);
    gemm_k<0, u16, 0><<<dim3(8, 16), 256, 0, stream>>>(XLN, wT, nullptr, nullptr, Vb, 2048, 1024, 1024, 0);
    krep_k<<<64, 256, 0, stream>>>(Kb, KREP);
    sinkhorn_k<<<16, 256, 0, stream>>>(KREP, wsort, Pm);
    sortmix_k<<<1024, 256, 0, stream>>>(Pm, Kb, Vb, KSb, VSb);
    attn_mfma_k<0><<<256, 256, 0, stream>>>(Qb, Kb, Vb, KSb, VSb, Ob);
    T(wo1, 1024);
    gemm_k<1, float, 0><<<dim3(8, 16), 256, 0, stream>>>(Ob, wT, nullptr, tgt_b, out_b, 2048, 1024, 1024, 0);
    ln_k<<<2048, 256, 0, stream>>>(out_b, ln2s, ln2b, XLN);
    conv_k<<<1024, 256, 0, stream>>>(enc_b, Eb);
    T(wq2, 1024);
    gemm_k<0, u16, 0><<<dim3(8, 16), 256, 0, stream>>>(XLN, wT, nullptr, nullptr, Qb, 2048, 1024, 1024, 0);
    T(wk2, 1024);
    gemm_k<0, u16, 0><<<dim3(8, 8), 256, 0, stream>>>(Eb, wT, nullptr, nullptr, Kb, 1024, 1024, 1024, 0);
    T(wv2, 1024);
    gemm_k<0, u16, 0><<<dim3(8, 8), 256, 0, stream>>>(Eb, wT, nullptr, nullptr, Vb, 1024, 1024, 1024, 0);
    attn_mfma_k<1><<<256, 256, 0, stream>>>(Qb, Kb, Vb, nullptr, nullptr, Ob);
    T(wo2, 1024);
    gemm_k<1, float, 0><<<dim3(8, 16), 256, 0, stream>>>(Ob, wT, nullptr, out_b, out_b, 2048, 1024, 1024, 0);
    ln_k<<<2048, 256, 0, stream>>>(out_b, ln3s, ln3b, XLN);
    for (int c = 0; c < 4; ++c) {
      T(w1 + (size_t)c * 1024, 4096);
      gemm_k<2, u16, 0><<<dim3(8, 16), 256, 0, stream>>>(XLN, wT, b1 + c * 1024, nullptr, Hc,
                                                         2048, 1024, 1024, 0);
      T(w2 + (size_t)c * 1024 * 1024, 1024);
      if (c < 3)
        gemm_k<1, float, 0><<<dim3(8, 16), 256, 0, stream>>>(Hc, wT, nullptr, out_b, out_b,
                                                             2048, 1024, 1024, 0);
      else
        gemm_k<3, float, 0><<<dim3(8, 16), 256, 0, stream>>>(Hc, wT, b2, out_b, out_b,
                                                             2048, 1024, 1024, 0);
    }
  }
}